// Round 1
// baseline (985.437 us; speedup 1.0000x reference)
//
#include <hip/hip_runtime.h>
#include <hip/hip_bf16.h>
#include <math.h>

#define N_NODES 25000
#define N_EDGES 250000
#define NH 4
#define F 256   // H*D
#define NEG_SLOPE 0.2f

// ---- float atomic-max via ordered-int key ----
__device__ inline int fkey(float f) {
    int i = __float_as_int(f);
    return i >= 0 ? i : (i ^ 0x7FFFFFFF);
}
__device__ inline float fdec(int i) {
    return __int_as_float(i >= 0 ? i : (i ^ 0x7FFFFFFF));
}

// ---------- CSR build ----------
__global__ void k_degree(const int* __restrict__ dst, int* deg) {
    int e = blockIdx.x * blockDim.x + threadIdx.x;
    if (e < N_EDGES) atomicAdd(&deg[dst[e]], 1);
}

__global__ __launch_bounds__(1024) void k_scan(const int* __restrict__ deg, int* rowptr) {
    __shared__ int sums[1024];
    const int CH = 25;  // 1024*25 = 25600 >= 25000
    int t = threadIdx.x;
    int base = t * CH;
    int s = 0;
    for (int i = 0; i < CH; ++i) {
        int idx = base + i;
        if (idx < N_NODES) s += deg[idx];
    }
    sums[t] = s;
    __syncthreads();
    for (int off = 1; off < 1024; off <<= 1) {
        int v = (t >= off) ? sums[t - off] : 0;
        __syncthreads();
        sums[t] += v;
        __syncthreads();
    }
    int prefix = (t == 0) ? 0 : sums[t - 1];
    for (int i = 0; i < CH; ++i) {
        int idx = base + i;
        if (idx < N_NODES) {
            rowptr[idx] = prefix;
            prefix += deg[idx];
        }
    }
    if (t == 1023) rowptr[N_NODES] = prefix;  // == E
}

__global__ void k_bucket(const int* __restrict__ src, const int* __restrict__ dst,
                         const int* __restrict__ rowptr, int* cursor,
                         int* esrc, int* ebid) {
    int e = blockIdx.x * blockDim.x + threadIdx.x;
    if (e >= N_EDGES) return;
    int d = dst[e];
    int p = atomicAdd(&cursor[d], 1);
    int slot = rowptr[d] + p;
    esrc[slot] = src[e];
    ebid[slot] = e;
}

// ---------- fp32 tiled GEMM: C[M,256] = A[M,256] @ B[256,256] ----------
#define BM 64
#define BN 64
#define BK 16
__global__ __launch_bounds__(256) void k_gemm(const float* __restrict__ A,
        const float* __restrict__ B, float* __restrict__ C, int M) {
    __shared__ float As[BK][BM];
    __shared__ float Bs[BK][BN];
    int tid = threadIdx.x;
    int bx = blockIdx.x & 3;   // 256/BN = 4 col tiles
    int by = blockIdx.x >> 2;
    int row0 = by * BM;
    int col0 = bx * BN;
    int tx = tid & 15, ty = tid >> 4;
    float acc[4][4] = {};
    int arow = tid >> 2;          // 0..63
    int acol4 = (tid & 3) * 4;    // k offset within tile
    int brow = tid >> 4;          // 0..15
    int bcol4 = (tid & 15) * 4;
    for (int kb = 0; kb < 256; kb += BK) {
        float4 av = make_float4(0.f, 0.f, 0.f, 0.f);
        int gr = row0 + arow;
        if (gr < M) av = *reinterpret_cast<const float4*>(&A[gr * 256 + kb + acol4]);
        As[acol4 + 0][arow] = av.x;
        As[acol4 + 1][arow] = av.y;
        As[acol4 + 2][arow] = av.z;
        As[acol4 + 3][arow] = av.w;
        float4 bv = *reinterpret_cast<const float4*>(&B[(kb + brow) * 256 + col0 + bcol4]);
        *reinterpret_cast<float4*>(&Bs[brow][bcol4]) = bv;
        __syncthreads();
        #pragma unroll
        for (int k = 0; k < BK; ++k) {
            float a[4], b[4];
            #pragma unroll
            for (int i = 0; i < 4; ++i) a[i] = As[k][ty * 4 + i];
            #pragma unroll
            for (int j = 0; j < 4; ++j) b[j] = Bs[k][tx * 4 + j];
            #pragma unroll
            for (int i = 0; i < 4; ++i)
                #pragma unroll
                for (int j = 0; j < 4; ++j)
                    acc[i][j] += a[i] * b[j];
        }
        __syncthreads();
    }
    #pragma unroll
    for (int i = 0; i < 4; ++i) {
        int gr = row0 + ty * 4 + i;
        if (gr < M) {
            *reinterpret_cast<float4*>(&C[gr * 256 + col0 + tx * 4]) =
                make_float4(acc[i][0], acc[i][1], acc[i][2], acc[i][3]);
        }
    }
}

// ---------- el/er: per-node per-head 64-dim dots ----------
__global__ __launch_bounds__(256) void k_elr(const float* __restrict__ feat,
        const float* __restrict__ al, const float* __restrict__ ar,
        float* __restrict__ el, float* __restrict__ er) {
    int n = blockIdx.x;
    int t = threadIdx.x;
    float v = feat[n * F + t];
    float pl = v * al[t];
    float pr = v * ar[t];
    #pragma unroll
    for (int off = 32; off >= 1; off >>= 1) {
        pl += __shfl_xor(pl, off);
        pr += __shfl_xor(pr, off);
    }
    if ((t & 63) == 0) {
        int h = t >> 6;
        el[n * NH + h] = pl;
        er[n * NH + h] = pr;
    }
}

__global__ void k_init(int* mI, float* s) {
    int i = blockIdx.x * blockDim.x + threadIdx.x;
    if (i < N_NODES * NH) { mI[i] = (int)0x80000000; s[i] = 0.f; }
}

// ---------- per-edge: e = lrelu(el[src]+er[dst]); atomicMax m[dst] ----------
__global__ void k_edge(const int* __restrict__ src, const int* __restrict__ dst,
        const float* __restrict__ el, const float* __restrict__ er,
        float* __restrict__ ee, int* __restrict__ mI) {
    int e = blockIdx.x * blockDim.x + threadIdx.x;
    if (e >= N_EDGES) return;
    int u = src[e], v = dst[e];
    float4 l4 = *reinterpret_cast<const float4*>(&el[u * NH]);
    float4 r4 = *reinterpret_cast<const float4*>(&er[v * NH]);
    float vals[4] = {l4.x + r4.x, l4.y + r4.y, l4.z + r4.z, l4.w + r4.w};
    float o[4];
    #pragma unroll
    for (int h = 0; h < 4; ++h) {
        float x = vals[h];
        x = x > 0.f ? x : NEG_SLOPE * x;
        o[h] = x;
        atomicMax(&mI[v * NH + h], fkey(x));
    }
    *reinterpret_cast<float4*>(&ee[e * NH]) = make_float4(o[0], o[1], o[2], o[3]);
}

// ---------- per-edge: a = exp(e - m[dst]); atomicAdd s[dst] ----------
__global__ void k_exp(const int* __restrict__ dst, const int* __restrict__ mI,
        float* __restrict__ ee, float* __restrict__ s) {
    int e = blockIdx.x * blockDim.x + threadIdx.x;
    if (e >= N_EDGES) return;
    int v = dst[e];
    float4 e4 = *reinterpret_cast<const float4*>(&ee[e * NH]);
    float o[4] = {e4.x, e4.y, e4.z, e4.w};
    #pragma unroll
    for (int h = 0; h < 4; ++h) {
        float m = fdec(mI[v * NH + h]);
        float a = expf(o[h] - m);
        o[h] = a;
        atomicAdd(&s[v * NH + h], a);
    }
    *reinterpret_cast<float4*>(&ee[e * NH]) = make_float4(o[0], o[1], o[2], o[3]);
}

// ---------- per-dst-node aggregation + bias + relu ----------
__global__ __launch_bounds__(256) void k_node(const float* __restrict__ feat,
        const float* __restrict__ a, const float* __restrict__ s,
        const int* __restrict__ rowptr, const int* __restrict__ esrc,
        const int* __restrict__ ebid, const float* __restrict__ bias,
        float* __restrict__ hout) {
    int n = blockIdx.x;
    int t = threadIdx.x;
    int h = t >> 6;
    float sv = s[n * NH + h];
    float inv_s = sv > 0.f ? 1.f / sv : 0.f;
    int r0 = rowptr[n], r1 = rowptr[n + 1];
    float acc = 0.f;
    for (int i = r0; i < r1; ++i) {
        int srcn = esrc[i];
        int eid = ebid[i];
        float av = a[eid * NH + h];
        acc += av * feat[srcn * F + t];
    }
    float o = acc * inv_s + bias[t];
    hout[n * F + t] = o > 0.f ? o : 0.f;
}

// ---------- final dot scores (pos then neg), one wave per edge ----------
__global__ __launch_bounds__(256) void k_score(const float* __restrict__ h,
        const int* __restrict__ src, const int* __restrict__ dst,
        const int* __restrict__ nsrc, const int* __restrict__ ndst,
        float* __restrict__ out) {
    int w = threadIdx.x >> 6;
    int l = threadIdx.x & 63;
    int g = blockIdx.x * 4 + w;
    int u, v;
    float* o;
    if (g < N_EDGES) {
        u = src[g]; v = dst[g]; o = out + (size_t)g * NH;
    } else if (g < 2 * N_EDGES) {
        int e = g - N_EDGES;
        u = nsrc[e]; v = ndst[e];
        o = out + (size_t)N_EDGES * NH + (size_t)e * NH;
    } else return;
    float4 hu = *reinterpret_cast<const float4*>(&h[u * F + l * 4]);
    float4 hv = *reinterpret_cast<const float4*>(&h[v * F + l * 4]);
    float p = hu.x * hv.x + hu.y * hv.y + hu.z * hv.z + hu.w * hv.w;
    p += __shfl_xor(p, 1);
    p += __shfl_xor(p, 2);
    p += __shfl_xor(p, 4);
    p += __shfl_xor(p, 8);
    if ((l & 15) == 0) o[l >> 4] = p;
}

extern "C" void kernel_launch(void* const* d_in, const int* in_sizes, int n_in,
                              void* d_out, int out_size, void* d_ws, size_t ws_size,
                              hipStream_t stream) {
    const float* x    = (const float*)d_in[0];
    const int* src    = (const int*)d_in[1];
    const int* dst    = (const int*)d_in[2];
    const int* nsrc   = (const int*)d_in[3];
    const int* ndst   = (const int*)d_in[4];
    const float* W[3]  = {(const float*)d_in[5], (const float*)d_in[9],  (const float*)d_in[13]};
    const float* al[3] = {(const float*)d_in[6], (const float*)d_in[10], (const float*)d_in[14]};
    const float* ar[3] = {(const float*)d_in[7], (const float*)d_in[11], (const float*)d_in[15]};
    const float* bs[3] = {(const float*)d_in[8], (const float*)d_in[12], (const float*)d_in[16]};

    char* p = (char*)d_ws;
    auto alloc = [&](size_t bytes) {
        char* r = p;
        p += (bytes + 255) & ~size_t(255);
        return r;
    };
    float* feat  = (float*)alloc(sizeof(float) * N_NODES * F);
    float* ha    = (float*)alloc(sizeof(float) * N_NODES * F);
    float* hb    = (float*)alloc(sizeof(float) * N_NODES * F);
    float* ee    = (float*)alloc(sizeof(float) * (size_t)N_EDGES * NH);
    float* el    = (float*)alloc(sizeof(float) * N_NODES * NH);
    float* er    = (float*)alloc(sizeof(float) * N_NODES * NH);
    float* sArr  = (float*)alloc(sizeof(float) * N_NODES * NH);
    int* mI      = (int*)alloc(sizeof(int) * N_NODES * NH);
    int* deg     = (int*)alloc(sizeof(int) * N_NODES);
    int* cursor  = (int*)alloc(sizeof(int) * N_NODES);
    int* rowptr  = (int*)alloc(sizeof(int) * (N_NODES + 1));
    int* esrc    = (int*)alloc(sizeof(int) * N_EDGES);
    int* ebid    = (int*)alloc(sizeof(int) * N_EDGES);

    hipMemsetAsync(deg, 0, sizeof(int) * N_NODES, stream);
    hipMemsetAsync(cursor, 0, sizeof(int) * N_NODES, stream);

    int eb = (N_EDGES + 255) / 256;
    k_degree<<<eb, 256, 0, stream>>>(dst, deg);
    k_scan<<<1, 1024, 0, stream>>>(deg, rowptr);
    k_bucket<<<eb, 256, 0, stream>>>(src, dst, rowptr, cursor, esrc, ebid);

    const float* in_h = x;
    float* outs[3] = {ha, hb, ha};
    int gemm_grid = ((N_NODES + BM - 1) / BM) * (F / BN);
    for (int L = 0; L < 3; ++L) {
        k_gemm<<<gemm_grid, 256, 0, stream>>>(in_h, W[L], feat, N_NODES);
        k_elr<<<N_NODES, 256, 0, stream>>>(feat, al[L], ar[L], el, er);
        k_init<<<(N_NODES * NH + 255) / 256, 256, 0, stream>>>(mI, sArr);
        k_edge<<<eb, 256, 0, stream>>>(src, dst, el, er, ee, mI);
        k_exp<<<eb, 256, 0, stream>>>(dst, mI, ee, sArr);
        k_node<<<N_NODES, 256, 0, stream>>>(feat, ee, sArr, rowptr, esrc, ebid, bs[L], outs[L]);
        in_h = outs[L];
    }
    k_score<<<(2 * N_EDGES + 3) / 4, 256, 0, stream>>>(outs[2], src, dst, nsrc, ndst, (float*)d_out);
}

// Round 3
// 738.859 us; speedup vs baseline: 1.3337x; 1.3337x over previous
//
#include <hip/hip_runtime.h>
#include <hip/hip_bf16.h>
#include <math.h>

#define N_NODES 25000
#define N_EDGES 250000
#define NH 4
#define F 256   // H*D
#define NEG_SLOPE 0.2f

typedef float  f32x4 __attribute__((ext_vector_type(4)));
typedef short  s16x8 __attribute__((ext_vector_type(8)));

__device__ inline ushort f2bf(float f) {
    uint u = __float_as_uint(f);
    u += 0x7FFF + ((u >> 16) & 1);   // round-to-nearest-even
    return (ushort)(u >> 16);
}
__device__ inline float bf2f(ushort s) { return __uint_as_float(((uint)s) << 16); }

// ---------- CSR build ----------
__global__ void k_degree(const int* __restrict__ dst, int* deg) {
    int e = blockIdx.x * blockDim.x + threadIdx.x;
    if (e < N_EDGES) atomicAdd(&deg[dst[e]], 1);
}

__global__ __launch_bounds__(1024) void k_scan(const int* __restrict__ deg, int* rowptr) {
    __shared__ int sums[1024];
    const int CH = 25;  // 1024*25 = 25600 >= 25000
    int t = threadIdx.x;
    int base = t * CH;
    int s = 0;
    for (int i = 0; i < CH; ++i) {
        int idx = base + i;
        if (idx < N_NODES) s += deg[idx];
    }
    sums[t] = s;
    __syncthreads();
    for (int off = 1; off < 1024; off <<= 1) {
        int v = (t >= off) ? sums[t - off] : 0;
        __syncthreads();
        sums[t] += v;
        __syncthreads();
    }
    int prefix = (t == 0) ? 0 : sums[t - 1];
    for (int i = 0; i < CH; ++i) {
        int idx = base + i;
        if (idx < N_NODES) {
            rowptr[idx] = prefix;
            prefix += deg[idx];
        }
    }
    if (t == 1023) rowptr[N_NODES] = prefix;
}

__global__ void k_bucket(const int* __restrict__ src, const int* __restrict__ dst,
                         const int* __restrict__ rowptr, int* cursor,
                         int* esrc, int* ebid) {
    int e = blockIdx.x * blockDim.x + threadIdx.x;
    if (e >= N_EDGES) return;
    int d = dst[e];
    int p = atomicAdd(&cursor[d], 1);
    int slot = rowptr[d] + p;
    esrc[slot] = src[e];
    ebid[slot] = e;
}

// ---------- W prep: transpose + bf16 split (once per call, tiny) ----------
__global__ __launch_bounds__(256) void k_wprep(const float* __restrict__ W,
        short* __restrict__ Hi, short* __restrict__ Lo) {
    __shared__ float T[64][65];
    int bk = (blockIdx.x & 3) * 64;   // k tile
    int bn = (blockIdx.x >> 2) * 64;  // n tile
    int t = threadIdx.x;
    int r = t >> 6, c = t & 63;
    #pragma unroll
    for (int i = 0; i < 64; i += 4)
        T[r + i][c] = W[(bk + r + i) * 256 + bn + c];
    __syncthreads();
    #pragma unroll
    for (int i = 0; i < 64; i += 4) {
        float w = T[c][r + i];
        ushort h = f2bf(w);
        Hi[(bn + r + i) * 256 + bk + c] = (short)h;
        Lo[(bn + r + i) * 256 + bk + c] = (short)f2bf(w - bf2f(h));
    }
}

// ---------- split-bf16 MFMA GEMM: C[M,256] = A[M,256] @ W[256,256] ----------
// A (fp32) split to hi/lo bf16 on the fly during LDS staging; 3 MFMA terms:
// hi*hi + lo*hi + hi*lo  (lo*lo dropped, ~2^-16 rel err).
// Block: 64 rows x full 256 cols, 4 waves (wave w -> cols w*64..w*64+63).
// LDS 16B-slot XOR swizzle: slot ^= (row>>1)&3 -> 2-way residual conflict (free).
__global__ __launch_bounds__(256) void k_gemm(const float* __restrict__ A,
        const short* __restrict__ WtHi, const short* __restrict__ WtLo,
        float* __restrict__ C, int M) {
    __shared__ short AsH[64][32], AsL[64][32];
    __shared__ short WsH[256][32], WsL[256][32];
    int tid = threadIdx.x;
    int w = tid >> 6, l = tid & 63;
    int row0 = blockIdx.x * 64;
    f32x4 acc[4][4];
    #pragma unroll
    for (int i = 0; i < 4; ++i)
        #pragma unroll
        for (int j = 0; j < 4; ++j)
            acc[i][j] = (f32x4){0.f, 0.f, 0.f, 0.f};

    int ar = tid >> 2;    // staging row 0..63
    int ak = tid & 3;     // 16B k-slot 0..3
    int sa = ak ^ ((ar >> 1) & 3);

    for (int kc = 0; kc < 256; kc += 32) {
        float4 a0 = make_float4(0.f, 0.f, 0.f, 0.f), a1 = a0;
        int gr = row0 + ar;
        if (gr < M) {
            a0 = *(const float4*)&A[gr * 256 + kc + ak * 8];
            a1 = *(const float4*)&A[gr * 256 + kc + ak * 8 + 4];
        }
        float av[8] = {a0.x, a0.y, a0.z, a0.w, a1.x, a1.y, a1.z, a1.w};
        s16x8 hi, lo;
        #pragma unroll
        for (int i = 0; i < 8; ++i) {
            ushort h = f2bf(av[i]);
            hi[i] = (short)h;
            lo[i] = (short)f2bf(av[i] - bf2f(h));
        }
        __syncthreads();  // previous iter's readers done
        *(s16x8*)&AsH[ar][sa * 8] = hi;
        *(s16x8*)&AsL[ar][sa * 8] = lo;
        #pragma unroll
        for (int r = 0; r < 4; ++r) {
            int n = (tid >> 2) + 64 * r;
            int sw = ak ^ ((n >> 1) & 3);
            *(s16x8*)&WsH[n][sw * 8] = *(const s16x8*)&WtHi[n * 256 + kc + ak * 8];
            *(s16x8*)&WsL[n][sw * 8] = *(const s16x8*)&WtLo[n * 256 + kc + ak * 8];
        }
        __syncthreads();

        int r16 = l & 15, kg = l >> 4;
        s16x8 ah[4], alo[4], bh[4], blo[4];
        #pragma unroll
        for (int i = 0; i < 4; ++i) {
            int r = i * 16 + r16;
            int s = (kg ^ ((r >> 1) & 3)) * 8;
            ah[i]  = *(const s16x8*)&AsH[r][s];
            alo[i] = *(const s16x8*)&AsL[r][s];
        }
        #pragma unroll
        for (int j = 0; j < 4; ++j) {
            int c = w * 64 + j * 16 + r16;
            int s = (kg ^ ((c >> 1) & 3)) * 8;
            bh[j]  = *(const s16x8*)&WsH[c][s];
            blo[j] = *(const s16x8*)&WsL[c][s];
        }
        #pragma unroll
        for (int i = 0; i < 4; ++i)
            #pragma unroll
            for (int j = 0; j < 4; ++j) {
                acc[i][j] = __builtin_amdgcn_mfma_f32_16x16x32_bf16(ah[i],  bh[j],  acc[i][j], 0, 0, 0);
                acc[i][j] = __builtin_amdgcn_mfma_f32_16x16x32_bf16(alo[i], bh[j],  acc[i][j], 0, 0, 0);
                acc[i][j] = __builtin_amdgcn_mfma_f32_16x16x32_bf16(ah[i],  blo[j], acc[i][j], 0, 0, 0);
            }
    }
    // epilogue: C/D layout col=lane&15, row=(lane>>4)*4+reg
    int r16 = l & 15, kg = l >> 4;
    #pragma unroll
    for (int i = 0; i < 4; ++i)
        #pragma unroll
        for (int j = 0; j < 4; ++j) {
            int c = w * 64 + j * 16 + r16;
            #pragma unroll
            for (int q = 0; q < 4; ++q) {
                int gr = row0 + i * 16 + kg * 4 + q;
                if (gr < M) C[gr * 256 + c] = acc[i][j][q];
            }
        }
}

// ---------- el/er: per-node per-head 64-dim dots ----------
__global__ __launch_bounds__(256) void k_elr(const float* __restrict__ feat,
        const float* __restrict__ al, const float* __restrict__ ar,
        float* __restrict__ el, float* __restrict__ er) {
    int n = blockIdx.x;
    int t = threadIdx.x;
    float v = feat[n * F + t];
    float pl = v * al[t];
    float pr = v * ar[t];
    #pragma unroll
    for (int off = 32; off >= 1; off >>= 1) {
        pl += __shfl_xor(pl, off);
        pr += __shfl_xor(pr, off);
    }
    if ((t & 63) == 0) {
        int h = t >> 6;
        el[n * NH + h] = pl;
        er[n * NH + h] = pr;
    }
}

// ---------- per-edge attention (no max subtraction; softmax shift-invariant) ----------
__global__ void k_att(const int* __restrict__ src, const int* __restrict__ dst,
        const float* __restrict__ el, const float* __restrict__ er,
        float* __restrict__ ee, float* __restrict__ s) {
    int e = blockIdx.x * blockDim.x + threadIdx.x;
    if (e >= N_EDGES) return;
    int u = src[e], v = dst[e];
    float4 l4 = *(const float4*)&el[u * NH];
    float4 r4 = *(const float4*)&er[v * NH];
    float o[4] = {l4.x + r4.x, l4.y + r4.y, l4.z + r4.z, l4.w + r4.w};
    #pragma unroll
    for (int h = 0; h < 4; ++h) {
        float x = o[h];
        x = x > 0.f ? x : NEG_SLOPE * x;
        float a = expf(x);
        o[h] = a;
        atomicAdd(&s[v * NH + h], a);
    }
    *(float4*)&ee[e * NH] = make_float4(o[0], o[1], o[2], o[3]);
}

// ---------- per-dst-node aggregation + bias + relu (+ optional bf16 copy) ----------
__global__ __launch_bounds__(256) void k_node(const float* __restrict__ feat,
        const float* __restrict__ a, const float* __restrict__ s,
        const int* __restrict__ rowptr, const int* __restrict__ esrc,
        const int* __restrict__ ebid, const float* __restrict__ bias,
        float* __restrict__ hout, short* __restrict__ hbf) {
    int n = blockIdx.x;
    int t = threadIdx.x;
    int h = t >> 6;
    float sv = s[n * NH + h];
    float inv_s = sv > 0.f ? 1.f / sv : 0.f;
    int r0 = rowptr[n], r1 = rowptr[n + 1];
    float acc = 0.f;
    for (int i = r0; i < r1; ++i) {
        int srcn = esrc[i];
        int eid = ebid[i];
        float av = a[eid * NH + h];
        acc += av * feat[srcn * F + t];
    }
    float o = acc * inv_s + bias[t];
    o = o > 0.f ? o : 0.f;
    hout[n * F + t] = o;
    if (hbf) hbf[n * F + t] = (short)f2bf(o);
}

// ---------- final dot scores from bf16 h3, one wave per edge ----------
__global__ __launch_bounds__(256) void k_score(const ushort* __restrict__ h,
        const int* __restrict__ src, const int* __restrict__ dst,
        const int* __restrict__ nsrc, const int* __restrict__ ndst,
        float* __restrict__ out) {
    int w = threadIdx.x >> 6;
    int l = threadIdx.x & 63;
    int g = blockIdx.x * 4 + w;
    int u, v;
    float* o;
    if (g < N_EDGES) {
        u = src[g]; v = dst[g]; o = out + (size_t)g * NH;
    } else if (g < 2 * N_EDGES) {
        int e = g - N_EDGES;
        u = nsrc[e]; v = ndst[e];
        o = out + (size_t)(N_EDGES + e) * NH;
    } else return;
    ushort4 a = *(const ushort4*)&h[u * F + l * 4];
    ushort4 b = *(const ushort4*)&h[v * F + l * 4];
    float p = bf2f(a.x) * bf2f(b.x) + bf2f(a.y) * bf2f(b.y)
            + bf2f(a.z) * bf2f(b.z) + bf2f(a.w) * bf2f(b.w);
    p += __shfl_xor(p, 1);
    p += __shfl_xor(p, 2);
    p += __shfl_xor(p, 4);
    p += __shfl_xor(p, 8);
    if ((l & 15) == 0) o[l >> 4] = p;
}

extern "C" void kernel_launch(void* const* d_in, const int* in_sizes, int n_in,
                              void* d_out, int out_size, void* d_ws, size_t ws_size,
                              hipStream_t stream) {
    const float* x    = (const float*)d_in[0];
    const int* src    = (const int*)d_in[1];
    const int* dst    = (const int*)d_in[2];
    const int* nsrc   = (const int*)d_in[3];
    const int* ndst   = (const int*)d_in[4];
    const float* W[3]  = {(const float*)d_in[5], (const float*)d_in[9],  (const float*)d_in[13]};
    const float* al[3] = {(const float*)d_in[6], (const float*)d_in[10], (const float*)d_in[14]};
    const float* ar[3] = {(const float*)d_in[7], (const float*)d_in[11], (const float*)d_in[15]};
    const float* bs[3] = {(const float*)d_in[8], (const float*)d_in[12], (const float*)d_in[16]};

    char* p = (char*)d_ws;
    auto alloc = [&](size_t bytes) {
        char* r = p;
        p += (bytes + 255) & ~size_t(255);
        return r;
    };
    float* feat  = (float*)alloc(sizeof(float) * N_NODES * F);
    float* ha    = (float*)alloc(sizeof(float) * N_NODES * F);
    float* hb    = (float*)alloc(sizeof(float) * N_NODES * F);
    float* ee    = (float*)alloc(sizeof(float) * (size_t)N_EDGES * NH);
    float* el    = (float*)alloc(sizeof(float) * N_NODES * NH);
    float* er    = (float*)alloc(sizeof(float) * N_NODES * NH);
    float* sArr  = (float*)alloc(sizeof(float) * N_NODES * NH);
    int* deg     = (int*)alloc(sizeof(int) * N_NODES);
    int* cursor  = (int*)alloc(sizeof(int) * N_NODES);
    int* rowptr  = (int*)alloc(sizeof(int) * (N_NODES + 1));
    int* esrc    = (int*)alloc(sizeof(int) * N_EDGES);
    int* ebid    = (int*)alloc(sizeof(int) * N_EDGES);
    short* wtHi[3], *wtLo[3];
    for (int i = 0; i < 3; ++i) {
        wtHi[i] = (short*)alloc(sizeof(short) * 256 * 256);
        wtLo[i] = (short*)alloc(sizeof(short) * 256 * 256);
    }
    short* h3bf = (short*)alloc(sizeof(short) * N_NODES * F);

    (void)hipMemsetAsync(deg, 0, sizeof(int) * N_NODES, stream);
    (void)hipMemsetAsync(cursor, 0, sizeof(int) * N_NODES, stream);

    int eb = (N_EDGES + 255) / 256;
    k_degree<<<eb, 256, 0, stream>>>(dst, deg);
    k_scan<<<1, 1024, 0, stream>>>(deg, rowptr);
    k_bucket<<<eb, 256, 0, stream>>>(src, dst, rowptr, cursor, esrc, ebid);
    for (int L = 0; L < 3; ++L)
        k_wprep<<<16, 256, 0, stream>>>(W[L], wtHi[L], wtLo[L]);

    const float* in_h = x;
    float* outs[3] = {ha, hb, ha};
    int gemm_grid = (N_NODES + 63) / 64;
    for (int L = 0; L < 3; ++L) {
        k_gemm<<<gemm_grid, 256, 0, stream>>>(in_h, wtHi[L], wtLo[L], feat, N_NODES);
        k_elr<<<N_NODES, 256, 0, stream>>>(feat, al[L], ar[L], el, er);
        (void)hipMemsetAsync(sArr, 0, sizeof(float) * N_NODES * NH, stream);
        k_att<<<eb, 256, 0, stream>>>(src, dst, el, er, ee, sArr);
        k_node<<<N_NODES, 256, 0, stream>>>(feat, ee, sArr, rowptr, esrc, ebid, bs[L],
                                            outs[L], (L == 2) ? h3bf : (short*)nullptr);
        in_h = outs[L];
    }
    k_score<<<(2 * N_EDGES + 3) / 4, 256, 0, stream>>>((const ushort*)h3bf, src, dst, nsrc, ndst, (float*)d_out);
}

// Round 4
// 522.803 us; speedup vs baseline: 1.8849x; 1.4133x over previous
//
#include <hip/hip_runtime.h>
#include <hip/hip_bf16.h>
#include <math.h>

#define N_NODES 25000
#define N_EDGES 250000
#define NH 4
#define F 256   // H*D
#define NEG_SLOPE 0.2f

typedef float  f32x4 __attribute__((ext_vector_type(4)));
typedef short  s16x8 __attribute__((ext_vector_type(8)));

__device__ inline ushort f2bf(float f) {
    uint u = __float_as_uint(f);
    u += 0x7FFF + ((u >> 16) & 1);   // round-to-nearest-even
    return (ushort)(u >> 16);
}
__device__ inline float bf2f(ushort s) { return __uint_as_float(((uint)s) << 16); }

// ---------- CSR build ----------
__global__ void k_degree(const int* __restrict__ dst, int* deg) {
    int e = blockIdx.x * blockDim.x + threadIdx.x;
    if (e < N_EDGES) atomicAdd(&deg[dst[e]], 1);
}

__global__ __launch_bounds__(1024) void k_scan(const int* __restrict__ deg, int* rowptr) {
    __shared__ int sums[1024];
    const int CH = 25;  // 1024*25 = 25600 >= 25000
    int t = threadIdx.x;
    int base = t * CH;
    int s = 0;
    for (int i = 0; i < CH; ++i) {
        int idx = base + i;
        if (idx < N_NODES) s += deg[idx];
    }
    sums[t] = s;
    __syncthreads();
    for (int off = 1; off < 1024; off <<= 1) {
        int v = (t >= off) ? sums[t - off] : 0;
        __syncthreads();
        sums[t] += v;
        __syncthreads();
    }
    int prefix = (t == 0) ? 0 : sums[t - 1];
    for (int i = 0; i < CH; ++i) {
        int idx = base + i;
        if (idx < N_NODES) {
            rowptr[idx] = prefix;
            prefix += deg[idx];
        }
    }
    if (t == 1023) rowptr[N_NODES] = prefix;
}

__global__ void k_bucket(const int* __restrict__ src, const int* __restrict__ dst,
                         const int* __restrict__ rowptr, int* cursor, int* esrc) {
    int e = blockIdx.x * blockDim.x + threadIdx.x;
    if (e >= N_EDGES) return;
    int d = dst[e];
    int p = atomicAdd(&cursor[d], 1);
    esrc[rowptr[d] + p] = src[e];
}

// ---------- W prep: transpose + bf16 split (once per call, tiny) ----------
__global__ __launch_bounds__(256) void k_wprep(const float* __restrict__ W,
        short* __restrict__ Hi, short* __restrict__ Lo) {
    __shared__ float T[64][65];
    int bk = (blockIdx.x & 3) * 64;   // k tile
    int bn = (blockIdx.x >> 2) * 64;  // n tile
    int t = threadIdx.x;
    int r = t >> 6, c = t & 63;
    #pragma unroll
    for (int i = 0; i < 64; i += 4)
        T[r + i][c] = W[(bk + r + i) * 256 + bn + c];
    __syncthreads();
    #pragma unroll
    for (int i = 0; i < 64; i += 4) {
        float w = T[c][r + i];
        ushort h = f2bf(w);
        Hi[(bn + r + i) * 256 + bk + c] = (short)h;
        Lo[(bn + r + i) * 256 + bk + c] = (short)f2bf(w - bf2f(h));
    }
}

// ---------- split-bf16 MFMA GEMM + fused el/er epilogue ----------
// C[M,256] = A[M,256] @ W[256,256]; 3 MFMA terms (hi*hi + lo*hi + hi*lo).
// Block: 64 rows x 256 cols, 4 waves; wave w owns cols of head w.
// Double-buffered LDS staging (reg prefetch), one barrier per K-chunk.
// Epilogue also computes el[n,h] = feat[n,h,:]·al[h], er likewise (shfl reduce).
__global__ __launch_bounds__(256) void k_gemm(const float* __restrict__ A,
        const short* __restrict__ WtHi, const short* __restrict__ WtLo,
        const float* __restrict__ alv, const float* __restrict__ arv,
        float* __restrict__ C, float* __restrict__ el, float* __restrict__ er,
        int M) {
    __shared__ short AsH[2][64][32], AsL[2][64][32];
    __shared__ short WsH[2][256][32], WsL[2][256][32];
    int tid = threadIdx.x;
    int w = tid >> 6, l = tid & 63;
    int row0 = blockIdx.x * 64;

    f32x4 acc[4][4];
    #pragma unroll
    for (int i = 0; i < 4; ++i)
        #pragma unroll
        for (int j = 0; j < 4; ++j)
            acc[i][j] = (f32x4){0.f, 0.f, 0.f, 0.f};

    const int sr = tid >> 2;                  // staging row 0..63
    const int sk = tid & 3;                   // 16B k-slot 0..3
    const int sa = sk ^ ((sr >> 1) & 3);      // A-side swizzled slot

    float4 a0, a1;
    s16x8 whr[4], wlr[4];

    // ---- prologue: load chunk 0 to regs ----
    {
        a0 = make_float4(0.f, 0.f, 0.f, 0.f); a1 = a0;
        int gr = row0 + sr;
        if (gr < M) {
            a0 = *(const float4*)&A[gr * 256 + sk * 8];
            a1 = *(const float4*)&A[gr * 256 + sk * 8 + 4];
        }
        #pragma unroll
        for (int r = 0; r < 4; ++r) {
            int n = sr + 64 * r;
            whr[r] = *(const s16x8*)&WtHi[n * 256 + sk * 8];
            wlr[r] = *(const s16x8*)&WtLo[n * 256 + sk * 8];
        }
    }
    // ---- write chunk 0 into buf 0 ----
    {
        float av[8] = {a0.x, a0.y, a0.z, a0.w, a1.x, a1.y, a1.z, a1.w};
        s16x8 hi, lo;
        #pragma unroll
        for (int i = 0; i < 8; ++i) {
            ushort h = f2bf(av[i]);
            hi[i] = (short)h;
            lo[i] = (short)f2bf(av[i] - bf2f(h));
        }
        *(s16x8*)&AsH[0][sr][sa * 8] = hi;
        *(s16x8*)&AsL[0][sr][sa * 8] = lo;
        #pragma unroll
        for (int r = 0; r < 4; ++r) {
            int n = sr + 64 * r;
            int sw = sk ^ ((n >> 1) & 3);
            *(s16x8*)&WsH[0][n][sw * 8] = whr[r];
            *(s16x8*)&WsL[0][n][sw * 8] = wlr[r];
        }
    }
    __syncthreads();

    const int r16 = l & 15, kg = l >> 4;
    for (int c = 0; c < 8; ++c) {
        const int b = c & 1;
        // prefetch chunk c+1 to regs (overlaps with MFMAs below)
        if (c < 7) {
            int kc = (c + 1) * 32;
            a0 = make_float4(0.f, 0.f, 0.f, 0.f); a1 = a0;
            int gr = row0 + sr;
            if (gr < M) {
                a0 = *(const float4*)&A[gr * 256 + kc + sk * 8];
                a1 = *(const float4*)&A[gr * 256 + kc + sk * 8 + 4];
            }
            #pragma unroll
            for (int r = 0; r < 4; ++r) {
                int n = sr + 64 * r;
                whr[r] = *(const s16x8*)&WtHi[n * 256 + kc + sk * 8];
                wlr[r] = *(const s16x8*)&WtLo[n * 256 + kc + sk * 8];
            }
        }
        // fragments from buf b
        s16x8 ah[4], alo[4], bh[4], blo[4];
        #pragma unroll
        for (int i = 0; i < 4; ++i) {
            int r = i * 16 + r16;
            int s = (kg ^ ((r >> 1) & 3)) * 8;
            ah[i]  = *(const s16x8*)&AsH[b][r][s];
            alo[i] = *(const s16x8*)&AsL[b][r][s];
        }
        #pragma unroll
        for (int j = 0; j < 4; ++j) {
            int cc = w * 64 + j * 16 + r16;
            int s = (kg ^ ((cc >> 1) & 3)) * 8;
            bh[j]  = *(const s16x8*)&WsH[b][cc][s];
            blo[j] = *(const s16x8*)&WsL[b][cc][s];
        }
        #pragma unroll
        for (int i = 0; i < 4; ++i)
            #pragma unroll
            for (int j = 0; j < 4; ++j) {
                acc[i][j] = __builtin_amdgcn_mfma_f32_16x16x32_bf16(ah[i],  bh[j],  acc[i][j], 0, 0, 0);
                acc[i][j] = __builtin_amdgcn_mfma_f32_16x16x32_bf16(alo[i], bh[j],  acc[i][j], 0, 0, 0);
                acc[i][j] = __builtin_amdgcn_mfma_f32_16x16x32_bf16(ah[i],  blo[j], acc[i][j], 0, 0, 0);
            }
        // write chunk c+1 into buf b^1
        if (c < 7) {
            float av[8] = {a0.x, a0.y, a0.z, a0.w, a1.x, a1.y, a1.z, a1.w};
            s16x8 hi, lo;
            #pragma unroll
            for (int i = 0; i < 8; ++i) {
                ushort h = f2bf(av[i]);
                hi[i] = (short)h;
                lo[i] = (short)f2bf(av[i] - bf2f(h));
            }
            *(s16x8*)&AsH[b ^ 1][sr][sa * 8] = hi;
            *(s16x8*)&AsL[b ^ 1][sr][sa * 8] = lo;
            #pragma unroll
            for (int r = 0; r < 4; ++r) {
                int n = sr + 64 * r;
                int sw = sk ^ ((n >> 1) & 3);
                *(s16x8*)&WsH[b ^ 1][n][sw * 8] = whr[r];
                *(s16x8*)&WsL[b ^ 1][n][sw * 8] = wlr[r];
            }
        }
        __syncthreads();
    }

    // ---- epilogue: C write + fused el/er ----
    float ac4[4], rc4[4];
    #pragma unroll
    for (int j = 0; j < 4; ++j) {
        ac4[j] = alv[w * 64 + j * 16 + r16];
        rc4[j] = arv[w * 64 + j * 16 + r16];
    }
    #pragma unroll
    for (int i = 0; i < 4; ++i) {
        #pragma unroll
        for (int q = 0; q < 4; ++q) {
            int gr = row0 + i * 16 + kg * 4 + q;
            float pel = 0.f, per = 0.f;
            #pragma unroll
            for (int j = 0; j < 4; ++j) {
                float v = acc[i][j][q];
                pel += v * ac4[j];
                per += v * rc4[j];
            }
            pel += __shfl_xor(pel, 1);  per += __shfl_xor(per, 1);
            pel += __shfl_xor(pel, 2);  per += __shfl_xor(per, 2);
            pel += __shfl_xor(pel, 4);  per += __shfl_xor(per, 4);
            pel += __shfl_xor(pel, 8);  per += __shfl_xor(per, 8);
            if (r16 == 0 && gr < M) {
                el[gr * NH + w] = pel;
                er[gr * NH + w] = per;
            }
        }
    }
    #pragma unroll
    for (int i = 0; i < 4; ++i)
        #pragma unroll
        for (int j = 0; j < 4; ++j) {
            int cc = w * 64 + j * 16 + r16;
            #pragma unroll
            for (int q = 0; q < 4; ++q) {
                int gr = row0 + i * 16 + kg * 4 + q;
                if (gr < M) C[gr * 256 + cc] = acc[i][j][q];
            }
        }
}

// ---------- fused attention + aggregation per dst node ----------
// alpha computed inline (softmax shift-invariance; no atomics, no edge arrays)
__global__ __launch_bounds__(256) void k_node(const float* __restrict__ feat,
        const float* __restrict__ el, const float* __restrict__ er,
        const int* __restrict__ rowptr, const int* __restrict__ esrc,
        const float* __restrict__ bias,
        float* __restrict__ hout, ushort* __restrict__ hbf) {
    int n = blockIdx.x;
    int t = threadIdx.x;
    int h = t >> 6;
    float ern = er[n * NH + h];
    int r0 = rowptr[n], r1 = rowptr[n + 1];
    float acc = 0.f, S = 0.f;
    for (int i = r0; i < r1; ++i) {
        int srcn = esrc[i];
        float e = el[srcn * NH + h] + ern;     // broadcast within wave
        e = e > 0.f ? e : NEG_SLOPE * e;
        float a = __expf(e);
        S += a;
        acc += a * feat[srcn * F + t];
    }
    float inv = S > 0.f ? 1.f / S : 0.f;
    float o = acc * inv + bias[t];
    o = o > 0.f ? o : 0.f;
    hout[n * F + t] = o;
    if (hbf) hbf[n * F + t] = f2bf(o);
}

// ---------- final dot scores from bf16 h3, one wave per edge ----------
__global__ __launch_bounds__(256) void k_score(const ushort* __restrict__ h,
        const int* __restrict__ src, const int* __restrict__ dst,
        const int* __restrict__ nsrc, const int* __restrict__ ndst,
        float* __restrict__ out) {
    int w = threadIdx.x >> 6;
    int l = threadIdx.x & 63;
    int g = blockIdx.x * 4 + w;
    int u, v;
    float* o;
    if (g < N_EDGES) {
        u = src[g]; v = dst[g]; o = out + (size_t)g * NH;
    } else if (g < 2 * N_EDGES) {
        int e = g - N_EDGES;
        u = nsrc[e]; v = ndst[e];
        o = out + (size_t)(N_EDGES + e) * NH;
    } else return;
    ushort4 a = *(const ushort4*)&h[u * F + l * 4];
    ushort4 b = *(const ushort4*)&h[v * F + l * 4];
    float p = bf2f(a.x) * bf2f(b.x) + bf2f(a.y) * bf2f(b.y)
            + bf2f(a.z) * bf2f(b.z) + bf2f(a.w) * bf2f(b.w);
    p += __shfl_xor(p, 1);
    p += __shfl_xor(p, 2);
    p += __shfl_xor(p, 4);
    p += __shfl_xor(p, 8);
    if ((l & 15) == 0) o[l >> 4] = p;
}

extern "C" void kernel_launch(void* const* d_in, const int* in_sizes, int n_in,
                              void* d_out, int out_size, void* d_ws, size_t ws_size,
                              hipStream_t stream) {
    const float* x    = (const float*)d_in[0];
    const int* src    = (const int*)d_in[1];
    const int* dst    = (const int*)d_in[2];
    const int* nsrc   = (const int*)d_in[3];
    const int* ndst   = (const int*)d_in[4];
    const float* W[3]  = {(const float*)d_in[5], (const float*)d_in[9],  (const float*)d_in[13]};
    const float* al[3] = {(const float*)d_in[6], (const float*)d_in[10], (const float*)d_in[14]};
    const float* ar[3] = {(const float*)d_in[7], (const float*)d_in[11], (const float*)d_in[15]};
    const float* bs[3] = {(const float*)d_in[8], (const float*)d_in[12], (const float*)d_in[16]};

    char* p = (char*)d_ws;
    auto alloc = [&](size_t bytes) {
        char* r = p;
        p += (bytes + 255) & ~size_t(255);
        return r;
    };
    float* feat  = (float*)alloc(sizeof(float) * N_NODES * F);
    float* ha    = (float*)alloc(sizeof(float) * N_NODES * F);
    float* hb    = (float*)alloc(sizeof(float) * N_NODES * F);
    float* el    = (float*)alloc(sizeof(float) * N_NODES * NH);
    float* er    = (float*)alloc(sizeof(float) * N_NODES * NH);
    int* deg     = (int*)alloc(sizeof(int) * N_NODES);
    int* cursor  = (int*)alloc(sizeof(int) * N_NODES);
    int* rowptr  = (int*)alloc(sizeof(int) * (N_NODES + 1));
    int* esrc    = (int*)alloc(sizeof(int) * N_EDGES);
    short* wtHi[3], *wtLo[3];
    for (int i = 0; i < 3; ++i) {
        wtHi[i] = (short*)alloc(sizeof(short) * 256 * 256);
        wtLo[i] = (short*)alloc(sizeof(short) * 256 * 256);
    }
    ushort* h3bf = (ushort*)alloc(sizeof(ushort) * N_NODES * F);

    (void)hipMemsetAsync(deg, 0, sizeof(int) * N_NODES, stream);
    (void)hipMemsetAsync(cursor, 0, sizeof(int) * N_NODES, stream);

    int eb = (N_EDGES + 255) / 256;
    k_degree<<<eb, 256, 0, stream>>>(dst, deg);
    k_scan<<<1, 1024, 0, stream>>>(deg, rowptr);
    k_bucket<<<eb, 256, 0, stream>>>(src, dst, rowptr, cursor, esrc);
    for (int L = 0; L < 3; ++L)
        k_wprep<<<16, 256, 0, stream>>>(W[L], wtHi[L], wtLo[L]);

    const float* in_h = x;
    float* outs[3] = {ha, hb, ha};
    int gemm_grid = (N_NODES + 63) / 64;
    for (int L = 0; L < 3; ++L) {
        k_gemm<<<gemm_grid, 256, 0, stream>>>(in_h, wtHi[L], wtLo[L], al[L], ar[L],
                                              feat, el, er, N_NODES);
        k_node<<<N_NODES, 256, 0, stream>>>(feat, el, er, rowptr, esrc, bs[L],
                                            outs[L], (L == 2) ? h3bf : (ushort*)nullptr);
        in_h = outs[L];
    }
    k_score<<<(2 * N_EDGES + 3) / 4, 256, 0, stream>>>(h3bf, src, dst, nsrc, ndst, (float*)d_out);
}

// Round 6
// 494.324 us; speedup vs baseline: 1.9935x; 1.0576x over previous
//
#include <hip/hip_runtime.h>
#include <hip/hip_bf16.h>
#include <math.h>

#define N_NODES 25000
#define N_EDGES 250000
#define NH 4
#define F 256   // H*D
#define NEG_SLOPE 0.2f

typedef float  f32x4 __attribute__((ext_vector_type(4)));
typedef short  s16x8 __attribute__((ext_vector_type(8)));

__device__ inline ushort f2bf(float f) {
    uint u = __float_as_uint(f);
    u += 0x7FFF + ((u >> 16) & 1);   // round-to-nearest-even
    return (ushort)(u >> 16);
}
__device__ inline float bf2f(ushort s) { return __uint_as_float(((uint)s) << 16); }

// ---------- CSR build ----------
__global__ void k_degree(const int* __restrict__ dst, int* deg) {
    int e = blockIdx.x * blockDim.x + threadIdx.x;
    if (e < N_EDGES) atomicAdd(&deg[dst[e]], 1);
}

__global__ __launch_bounds__(1024) void k_scan(const int* __restrict__ deg, int* rowptr) {
    __shared__ int sums[1024];
    const int CH = 25;
    int t = threadIdx.x;
    int base = t * CH;
    int s = 0;
    for (int i = 0; i < CH; ++i) {
        int idx = base + i;
        if (idx < N_NODES) s += deg[idx];
    }
    sums[t] = s;
    __syncthreads();
    for (int off = 1; off < 1024; off <<= 1) {
        int v = (t >= off) ? sums[t - off] : 0;
        __syncthreads();
        sums[t] += v;
        __syncthreads();
    }
    int prefix = (t == 0) ? 0 : sums[t - 1];
    for (int i = 0; i < CH; ++i) {
        int idx = base + i;
        if (idx < N_NODES) {
            rowptr[idx] = prefix;
            prefix += deg[idx];
        }
    }
    if (t == 1023) rowptr[N_NODES] = prefix;
}

__global__ void k_bucket(const int* __restrict__ src, const int* __restrict__ dst,
                         const int* __restrict__ rowptr, int* cursor, int* esrc) {
    int e = blockIdx.x * blockDim.x + threadIdx.x;
    if (e >= N_EDGES) return;
    int d = dst[e];
    int p = atomicAdd(&cursor[d], 1);
    esrc[rowptr[d] + p] = src[e];
}

// ---------- W prep: transpose + bf16 split ----------
__global__ __launch_bounds__(256) void k_wprep(const float* __restrict__ W,
        short* __restrict__ Hi, short* __restrict__ Lo) {
    __shared__ float T[64][65];
    int bk = (blockIdx.x & 3) * 64;
    int bn = (blockIdx.x >> 2) * 64;
    int t = threadIdx.x;
    int r = t >> 6, c = t & 63;
    #pragma unroll
    for (int i = 0; i < 64; i += 4)
        T[r + i][c] = W[(bk + r + i) * 256 + bn + c];
    __syncthreads();
    #pragma unroll
    for (int i = 0; i < 64; i += 4) {
        float w = T[c][r + i];
        ushort h = f2bf(w);
        Hi[(bn + r + i) * 256 + bk + c] = (short)h;
        Lo[(bn + r + i) * 256 + bk + c] = (short)f2bf(w - bf2f(h));
    }
}

// ---------- split-bf16 MFMA GEMM + fused el/er epilogue; bf16 feat out ----------
__global__ __launch_bounds__(256) void k_gemm(const float* __restrict__ A,
        const short* __restrict__ WtHi, const short* __restrict__ WtLo,
        const float* __restrict__ alv, const float* __restrict__ arv,
        ushort* __restrict__ Cbf, float* __restrict__ el, float* __restrict__ er,
        int M) {
    __shared__ short AsH[2][64][32], AsL[2][64][32];
    __shared__ short WsH[2][256][32], WsL[2][256][32];
    int tid = threadIdx.x;
    int w = tid >> 6, l = tid & 63;
    int row0 = blockIdx.x * 64;

    f32x4 acc[4][4];
    #pragma unroll
    for (int i = 0; i < 4; ++i)
        #pragma unroll
        for (int j = 0; j < 4; ++j)
            acc[i][j] = (f32x4){0.f, 0.f, 0.f, 0.f};

    const int sr = tid >> 2;
    const int sk = tid & 3;
    const int sa = sk ^ ((sr >> 1) & 3);

    float4 a0, a1;
    s16x8 whr[4], wlr[4];

    {
        a0 = make_float4(0.f, 0.f, 0.f, 0.f); a1 = a0;
        int gr = row0 + sr;
        if (gr < M) {
            a0 = *(const float4*)&A[gr * 256 + sk * 8];
            a1 = *(const float4*)&A[gr * 256 + sk * 8 + 4];
        }
        #pragma unroll
        for (int r = 0; r < 4; ++r) {
            int n = sr + 64 * r;
            whr[r] = *(const s16x8*)&WtHi[n * 256 + sk * 8];
            wlr[r] = *(const s16x8*)&WtLo[n * 256 + sk * 8];
        }
    }
    {
        float av[8] = {a0.x, a0.y, a0.z, a0.w, a1.x, a1.y, a1.z, a1.w};
        s16x8 hi, lo;
        #pragma unroll
        for (int i = 0; i < 8; ++i) {
            ushort h = f2bf(av[i]);
            hi[i] = (short)h;
            lo[i] = (short)f2bf(av[i] - bf2f(h));
        }
        *(s16x8*)&AsH[0][sr][sa * 8] = hi;
        *(s16x8*)&AsL[0][sr][sa * 8] = lo;
        #pragma unroll
        for (int r = 0; r < 4; ++r) {
            int n = sr + 64 * r;
            int sw = sk ^ ((n >> 1) & 3);
            *(s16x8*)&WsH[0][n][sw * 8] = whr[r];
            *(s16x8*)&WsL[0][n][sw * 8] = wlr[r];
        }
    }
    __syncthreads();

    const int r16 = l & 15, kg = l >> 4;
    for (int c = 0; c < 8; ++c) {
        const int b = c & 1;
        if (c < 7) {
            int kc = (c + 1) * 32;
            a0 = make_float4(0.f, 0.f, 0.f, 0.f); a1 = a0;
            int gr = row0 + sr;
            if (gr < M) {
                a0 = *(const float4*)&A[gr * 256 + kc + sk * 8];
                a1 = *(const float4*)&A[gr * 256 + kc + sk * 8 + 4];
            }
            #pragma unroll
            for (int r = 0; r < 4; ++r) {
                int n = sr + 64 * r;
                whr[r] = *(const s16x8*)&WtHi[n * 256 + kc + sk * 8];
                wlr[r] = *(const s16x8*)&WtLo[n * 256 + kc + sk * 8];
            }
        }
        s16x8 ah[4], alo[4], bh[4], blo[4];
        #pragma unroll
        for (int i = 0; i < 4; ++i) {
            int r = i * 16 + r16;
            int s = (kg ^ ((r >> 1) & 3)) * 8;
            ah[i]  = *(const s16x8*)&AsH[b][r][s];
            alo[i] = *(const s16x8*)&AsL[b][r][s];
        }
        #pragma unroll
        for (int j = 0; j < 4; ++j) {
            int cc = w * 64 + j * 16 + r16;
            int s = (kg ^ ((cc >> 1) & 3)) * 8;
            bh[j]  = *(const s16x8*)&WsH[b][cc][s];
            blo[j] = *(const s16x8*)&WsL[b][cc][s];
        }
        #pragma unroll
        for (int i = 0; i < 4; ++i)
            #pragma unroll
            for (int j = 0; j < 4; ++j) {
                acc[i][j] = __builtin_amdgcn_mfma_f32_16x16x32_bf16(ah[i],  bh[j],  acc[i][j], 0, 0, 0);
                acc[i][j] = __builtin_amdgcn_mfma_f32_16x16x32_bf16(alo[i], bh[j],  acc[i][j], 0, 0, 0);
                acc[i][j] = __builtin_amdgcn_mfma_f32_16x16x32_bf16(ah[i],  blo[j], acc[i][j], 0, 0, 0);
            }
        if (c < 7) {
            float av[8] = {a0.x, a0.y, a0.z, a0.w, a1.x, a1.y, a1.z, a1.w};
            s16x8 hi, lo;
            #pragma unroll
            for (int i = 0; i < 8; ++i) {
                ushort h = f2bf(av[i]);
                hi[i] = (short)h;
                lo[i] = (short)f2bf(av[i] - bf2f(h));
            }
            *(s16x8*)&AsH[b ^ 1][sr][sa * 8] = hi;
            *(s16x8*)&AsL[b ^ 1][sr][sa * 8] = lo;
            #pragma unroll
            for (int r = 0; r < 4; ++r) {
                int n = sr + 64 * r;
                int sw = sk ^ ((n >> 1) & 3);
                *(s16x8*)&WsH[b ^ 1][n][sw * 8] = whr[r];
                *(s16x8*)&WsL[b ^ 1][n][sw * 8] = wlr[r];
            }
        }
        __syncthreads();
    }

    // ---- epilogue: fused el/er + bf16 feat write ----
    float ac4[4], rc4[4];
    #pragma unroll
    for (int j = 0; j < 4; ++j) {
        ac4[j] = alv[w * 64 + j * 16 + r16];
        rc4[j] = arv[w * 64 + j * 16 + r16];
    }
    #pragma unroll
    for (int i = 0; i < 4; ++i) {
        #pragma unroll
        for (int q = 0; q < 4; ++q) {
            int gr = row0 + i * 16 + kg * 4 + q;
            float pel = 0.f, per = 0.f;
            #pragma unroll
            for (int j = 0; j < 4; ++j) {
                float v = acc[i][j][q];
                pel += v * ac4[j];
                per += v * rc4[j];
            }
            pel += __shfl_xor(pel, 1);  per += __shfl_xor(per, 1);
            pel += __shfl_xor(pel, 2);  per += __shfl_xor(per, 2);
            pel += __shfl_xor(pel, 4);  per += __shfl_xor(per, 4);
            pel += __shfl_xor(pel, 8);  per += __shfl_xor(per, 8);
            if (r16 == 0 && gr < M) {
                el[gr * NH + w] = pel;
                er[gr * NH + w] = per;
            }
        }
    }
    #pragma unroll
    for (int i = 0; i < 4; ++i)
        #pragma unroll
        for (int j = 0; j < 4; ++j) {
            int cc = w * 64 + j * 16 + r16;
            #pragma unroll
            for (int q = 0; q < 4; ++q) {
                int gr = row0 + i * 16 + kg * 4 + q;
                if (gr < M) Cbf[gr * 256 + cc] = f2bf(acc[i][j][q]);
            }
        }
}

// ---------- fused attention + aggregation: 2 nodes/block, 128 thr/node ----------
// featbf gathered as bf16 (dword = 2 cols/thread), fp32 accumulate.
__global__ __launch_bounds__(256) void k_node(const ushort* __restrict__ featbf,
        const float* __restrict__ el, const float* __restrict__ er,
        const int* __restrict__ rowptr, const int* __restrict__ esrc,
        const float* __restrict__ bias,
        float* __restrict__ hout, ushort* __restrict__ hbf) {
    int t = threadIdx.x;
    int n = blockIdx.x * 2 + (t >> 7);
    if (n >= N_NODES) return;
    int tt = t & 127;
    int c0 = tt * 2;           // columns c0, c0+1
    int h = tt >> 5;           // head
    float ern = er[n * NH + h];
    int r0 = rowptr[n], r1 = rowptr[n + 1];
    float acc0 = 0.f, acc1 = 0.f, S = 0.f;
    for (int i = r0; i < r1; ++i) {
        int srcn = esrc[i];
        float e = el[srcn * NH + h] + ern;
        e = e > 0.f ? e : NEG_SLOPE * e;
        float a = __expf(e);
        S += a;
        uint pk = *(const uint*)&featbf[srcn * F + c0];
        acc0 += a * bf2f((ushort)(pk & 0xFFFF));
        acc1 += a * bf2f((ushort)(pk >> 16));
    }
    float inv = S > 0.f ? 1.f / S : 0.f;
    float o0 = acc0 * inv + bias[c0];
    float o1 = acc1 * inv + bias[c0 + 1];
    o0 = o0 > 0.f ? o0 : 0.f;
    o1 = o1 > 0.f ? o1 : 0.f;
    if (hout) *(float2*)&hout[n * F + c0] = make_float2(o0, o1);
    if (hbf) {
        uint pk = (uint)f2bf(o0) | ((uint)f2bf(o1) << 16);
        *(uint*)&hbf[n * F + c0] = pk;
    }
}

// ---------- final dot scores from bf16 h3, one wave per edge ----------
__global__ __launch_bounds__(256) void k_score(const ushort* __restrict__ h,
        const int* __restrict__ src, const int* __restrict__ dst,
        const int* __restrict__ nsrc, const int* __restrict__ ndst,
        float* __restrict__ out) {
    int w = threadIdx.x >> 6;
    int l = threadIdx.x & 63;
    int g = blockIdx.x * 4 + w;
    int u, v;
    float* o;
    if (g < N_EDGES) {
        u = src[g]; v = dst[g]; o = out + (size_t)g * NH;
    } else if (g < 2 * N_EDGES) {
        int e = g - N_EDGES;
        u = nsrc[e]; v = ndst[e];
        o = out + (size_t)(N_EDGES + e) * NH;
    } else return;
    ushort4 a = *(const ushort4*)&h[u * F + l * 4];
    ushort4 b = *(const ushort4*)&h[v * F + l * 4];
    float p = bf2f(a.x) * bf2f(b.x) + bf2f(a.y) * bf2f(b.y)
            + bf2f(a.z) * bf2f(b.z) + bf2f(a.w) * bf2f(b.w);
    p += __shfl_xor(p, 1);
    p += __shfl_xor(p, 2);
    p += __shfl_xor(p, 4);
    p += __shfl_xor(p, 8);
    if ((l & 15) == 0) o[l >> 4] = p;
}

extern "C" void kernel_launch(void* const* d_in, const int* in_sizes, int n_in,
                              void* d_out, int out_size, void* d_ws, size_t ws_size,
                              hipStream_t stream) {
    const float* x    = (const float*)d_in[0];
    const int* src    = (const int*)d_in[1];
    const int* dst    = (const int*)d_in[2];
    const int* nsrc   = (const int*)d_in[3];
    const int* ndst   = (const int*)d_in[4];
    const float* W[3]  = {(const float*)d_in[5], (const float*)d_in[9],  (const float*)d_in[13]};
    const float* al[3] = {(const float*)d_in[6], (const float*)d_in[10], (const float*)d_in[14]};
    const float* ar[3] = {(const float*)d_in[7], (const float*)d_in[11], (const float*)d_in[15]};
    const float* bs[3] = {(const float*)d_in[8], (const float*)d_in[12], (const float*)d_in[16]};

    char* p = (char*)d_ws;
    auto alloc = [&](size_t bytes) {
        char* r = p;
        p += (bytes + 255) & ~size_t(255);
        return r;
    };
    ushort* featbf = (ushort*)alloc(sizeof(ushort) * N_NODES * F);
    float* ha    = (float*)alloc(sizeof(float) * N_NODES * F);
    float* hb    = (float*)alloc(sizeof(float) * N_NODES * F);
    float* el    = (float*)alloc(sizeof(float) * N_NODES * NH);
    float* er    = (float*)alloc(sizeof(float) * N_NODES * NH);
    int* deg     = (int*)alloc(sizeof(int) * N_NODES);
    int* cursor  = (int*)alloc(sizeof(int) * N_NODES);
    int* rowptr  = (int*)alloc(sizeof(int) * (N_NODES + 1));
    int* esrc    = (int*)alloc(sizeof(int) * N_EDGES);
    short* wtHi[3], *wtLo[3];
    for (int i = 0; i < 3; ++i) {
        wtHi[i] = (short*)alloc(sizeof(short) * 256 * 256);
        wtLo[i] = (short*)alloc(sizeof(short) * 256 * 256);
    }
    ushort* h3bf = (ushort*)alloc(sizeof(ushort) * N_NODES * F);

    (void)hipMemsetAsync(deg, 0, sizeof(int) * N_NODES, stream);
    (void)hipMemsetAsync(cursor, 0, sizeof(int) * N_NODES, stream);

    int eb = (N_EDGES + 255) / 256;
    k_degree<<<eb, 256, 0, stream>>>(dst, deg);
    k_scan<<<1, 1024, 0, stream>>>(deg, rowptr);
    k_bucket<<<eb, 256, 0, stream>>>(src, dst, rowptr, cursor, esrc);
    for (int L = 0; L < 3; ++L)
        k_wprep<<<16, 256, 0, stream>>>(W[L], wtHi[L], wtLo[L]);

    const float* in_h = x;
    float* outs[3] = {ha, hb, nullptr};
    int gemm_grid = (N_NODES + 63) / 64;
    int node_grid = (N_NODES + 1) / 2;
    for (int L = 0; L < 3; ++L) {
        k_gemm<<<gemm_grid, 256, 0, stream>>>(in_h, wtHi[L], wtLo[L], al[L], ar[L],
                                              featbf, el, er, N_NODES);
        k_node<<<node_grid, 256, 0, stream>>>(featbf, el, er, rowptr, esrc, bs[L],
                                              outs[L], (L == 2) ? h3bf : (ushort*)nullptr);
        in_h = outs[L];
    }
    k_score<<<(2 * N_EDGES + 3) / 4, 256, 0, stream>>>(h3bf, src, dst, nsrc, ndst, (float*)d_out);
}

// Round 8
// 400.869 us; speedup vs baseline: 2.4583x; 1.2331x over previous
//
#include <hip/hip_runtime.h>
#include <hip/hip_bf16.h>
#include <math.h>

#define N_NODES 25000
#define N_EDGES 250000
#define NH 4
#define F 256   // H*D
#define NEG_SLOPE 0.2f

typedef float  f32x4 __attribute__((ext_vector_type(4)));
typedef short  s16x8 __attribute__((ext_vector_type(8)));
typedef ushort u16x8 __attribute__((ext_vector_type(8)));

__device__ inline ushort f2bf(float f) {
    uint u = __float_as_uint(f);
    u += 0x7FFF + ((u >> 16) & 1);   // round-to-nearest-even
    return (ushort)(u >> 16);
}
__device__ inline float bf2f(ushort s) { return __uint_as_float(((uint)s) << 16); }

// ---------- x -> bf16 cast ----------
__global__ __launch_bounds__(256) void k_cast(const float* __restrict__ x,
                                              ushort* __restrict__ xb) {
    int i = blockIdx.x * blockDim.x + threadIdx.x;
    if (i * 4 >= N_NODES * F) return;
    float4 v = *(const float4*)&x[i * 4];
    ushort4 o;
    o.x = f2bf(v.x); o.y = f2bf(v.y); o.z = f2bf(v.z); o.w = f2bf(v.w);
    *(ushort4*)&xb[i * 4] = o;
}

// ---------- CSR build ----------
__global__ void k_degree(const int* __restrict__ dst, int* deg) {
    int e = blockIdx.x * blockDim.x + threadIdx.x;
    if (e < N_EDGES) atomicAdd(&deg[dst[e]], 1);
}

__global__ __launch_bounds__(1024) void k_scan(const int* __restrict__ deg, int* rowptr) {
    __shared__ int sums[1024];
    const int CH = 25;
    int t = threadIdx.x;
    int base = t * CH;
    int s = 0;
    for (int i = 0; i < CH; ++i) {
        int idx = base + i;
        if (idx < N_NODES) s += deg[idx];
    }
    sums[t] = s;
    __syncthreads();
    for (int off = 1; off < 1024; off <<= 1) {
        int v = (t >= off) ? sums[t - off] : 0;
        __syncthreads();
        sums[t] += v;
        __syncthreads();
    }
    int prefix = (t == 0) ? 0 : sums[t - 1];
    for (int i = 0; i < CH; ++i) {
        int idx = base + i;
        if (idx < N_NODES) {
            rowptr[idx] = prefix;
            prefix += deg[idx];
        }
    }
    if (t == 1023) rowptr[N_NODES] = prefix;
}

__global__ void k_bucket(const int* __restrict__ src, const int* __restrict__ dst,
                         const int* __restrict__ rowptr, int* cursor, int* esrc) {
    int e = blockIdx.x * blockDim.x + threadIdx.x;
    if (e >= N_EDGES) return;
    int d = dst[e];
    int p = atomicAdd(&cursor[d], 1);
    esrc[rowptr[d] + p] = src[e];
}

// ---------- W prep: transpose + bf16 split ----------
__global__ __launch_bounds__(256) void k_wprep(const float* __restrict__ W,
        short* __restrict__ Hi, short* __restrict__ Lo) {
    __shared__ float T[64][65];
    int bk = (blockIdx.x & 3) * 64;
    int bn = (blockIdx.x >> 2) * 64;
    int t = threadIdx.x;
    int r = t >> 6, c = t & 63;
    #pragma unroll
    for (int i = 0; i < 64; i += 4)
        T[r + i][c] = W[(bk + r + i) * 256 + bn + c];
    __syncthreads();
    #pragma unroll
    for (int i = 0; i < 64; i += 4) {
        float w = T[c][r + i];
        ushort h = f2bf(w);
        Hi[(bn + r + i) * 256 + bk + c] = (short)h;
        Lo[(bn + r + i) * 256 + bk + c] = (short)f2bf(w - bf2f(h));
    }
}

// ---------- bf16-A MFMA GEMM (2 terms: A*Whi + A*Wlo) + fused el/er ----------
// A is bf16 (exact) -> no A split needed. W split hi/lo gives ~fp19 weights.
__global__ __launch_bounds__(256) void k_gemm(const ushort* __restrict__ A,
        const short* __restrict__ WtHi, const short* __restrict__ WtLo,
        const float* __restrict__ alv, const float* __restrict__ arv,
        ushort* __restrict__ Cbf, float* __restrict__ el, float* __restrict__ er,
        int M) {
    __shared__ short As[2][64][32];
    __shared__ short WsH[2][256][32], WsL[2][256][32];
    int tid = threadIdx.x;
    int w = tid >> 6, l = tid & 63;
    int row0 = blockIdx.x * 64;

    f32x4 acc[4][4];
    #pragma unroll
    for (int i = 0; i < 4; ++i)
        #pragma unroll
        for (int j = 0; j < 4; ++j)
            acc[i][j] = (f32x4){0.f, 0.f, 0.f, 0.f};

    const int sr = tid >> 2;              // staging row 0..63
    const int sk = tid & 3;               // 16B k-slot 0..3
    const int sa = sk ^ ((sr >> 1) & 3);  // swizzled slot

    s16x8 aReg;
    s16x8 whr[4], wlr[4];

    // prologue: chunk 0 -> regs -> buf 0
    {
        int gr = row0 + sr;
        aReg = (s16x8){0,0,0,0,0,0,0,0};
        if (gr < M) aReg = *(const s16x8*)&A[gr * 256 + sk * 8];
        #pragma unroll
        for (int r = 0; r < 4; ++r) {
            int n = sr + 64 * r;
            whr[r] = *(const s16x8*)&WtHi[n * 256 + sk * 8];
            wlr[r] = *(const s16x8*)&WtLo[n * 256 + sk * 8];
        }
        *(s16x8*)&As[0][sr][sa * 8] = aReg;
        #pragma unroll
        for (int r = 0; r < 4; ++r) {
            int n = sr + 64 * r;
            int sw = sk ^ ((n >> 1) & 3);
            *(s16x8*)&WsH[0][n][sw * 8] = whr[r];
            *(s16x8*)&WsL[0][n][sw * 8] = wlr[r];
        }
    }
    __syncthreads();

    const int r16 = l & 15, kg = l >> 4;
    for (int c = 0; c < 8; ++c) {
        const int b = c & 1;
        if (c < 7) {
            int kc = (c + 1) * 32;
            int gr = row0 + sr;
            aReg = (s16x8){0,0,0,0,0,0,0,0};
            if (gr < M) aReg = *(const s16x8*)&A[gr * 256 + kc + sk * 8];
            #pragma unroll
            for (int r = 0; r < 4; ++r) {
                int n = sr + 64 * r;
                whr[r] = *(const s16x8*)&WtHi[n * 256 + kc + sk * 8];
                wlr[r] = *(const s16x8*)&WtLo[n * 256 + kc + sk * 8];
            }
        }
        s16x8 ah[4], bh[4], blo[4];
        #pragma unroll
        for (int i = 0; i < 4; ++i) {
            int r = i * 16 + r16;
            int s = (kg ^ ((r >> 1) & 3)) * 8;
            ah[i] = *(const s16x8*)&As[b][r][s];
        }
        #pragma unroll
        for (int j = 0; j < 4; ++j) {
            int cc = w * 64 + j * 16 + r16;
            int s = (kg ^ ((cc >> 1) & 3)) * 8;
            bh[j]  = *(const s16x8*)&WsH[b][cc][s];
            blo[j] = *(const s16x8*)&WsL[b][cc][s];
        }
        #pragma unroll
        for (int i = 0; i < 4; ++i)
            #pragma unroll
            for (int j = 0; j < 4; ++j) {
                acc[i][j] = __builtin_amdgcn_mfma_f32_16x16x32_bf16(ah[i], bh[j],  acc[i][j], 0, 0, 0);
                acc[i][j] = __builtin_amdgcn_mfma_f32_16x16x32_bf16(ah[i], blo[j], acc[i][j], 0, 0, 0);
            }
        if (c < 7) {
            *(s16x8*)&As[b ^ 1][sr][sa * 8] = aReg;
            #pragma unroll
            for (int r = 0; r < 4; ++r) {
                int n = sr + 64 * r;
                int sw = sk ^ ((n >> 1) & 3);
                *(s16x8*)&WsH[b ^ 1][n][sw * 8] = whr[r];
                *(s16x8*)&WsL[b ^ 1][n][sw * 8] = wlr[r];
            }
        }
        __syncthreads();
    }

    // ---- epilogue: fused el/er + bf16 feat write ----
    float ac4[4], rc4[4];
    #pragma unroll
    for (int j = 0; j < 4; ++j) {
        ac4[j] = alv[w * 64 + j * 16 + r16];
        rc4[j] = arv[w * 64 + j * 16 + r16];
    }
    #pragma unroll
    for (int i = 0; i < 4; ++i) {
        #pragma unroll
        for (int q = 0; q < 4; ++q) {
            int gr = row0 + i * 16 + kg * 4 + q;
            float pel = 0.f, per = 0.f;
            #pragma unroll
            for (int j = 0; j < 4; ++j) {
                float v = acc[i][j][q];
                pel += v * ac4[j];
                per += v * rc4[j];
            }
            pel += __shfl_xor(pel, 1);  per += __shfl_xor(per, 1);
            pel += __shfl_xor(pel, 2);  per += __shfl_xor(per, 2);
            pel += __shfl_xor(pel, 4);  per += __shfl_xor(per, 4);
            pel += __shfl_xor(pel, 8);  per += __shfl_xor(per, 8);
            if (r16 == 0 && gr < M) {
                el[gr * NH + w] = pel;
                er[gr * NH + w] = per;
            }
        }
    }
    #pragma unroll
    for (int i = 0; i < 4; ++i)
        #pragma unroll
        for (int j = 0; j < 4; ++j) {
            int cc = w * 64 + j * 16 + r16;
            #pragma unroll
            for (int q = 0; q < 4; ++q) {
                int gr = row0 + i * 16 + kg * 4 + q;
                if (gr < M) Cbf[gr * 256 + cc] = f2bf(acc[i][j][q]);
            }
        }
}

// ---------- fused attention + aggregation: 2 nodes/block, 128 thr/node ----------
__global__ __launch_bounds__(256) void k_node(const ushort* __restrict__ featbf,
        const float* __restrict__ el, const float* __restrict__ er,
        const int* __restrict__ rowptr, const int* __restrict__ esrc,
        const float* __restrict__ bias,
        ushort* __restrict__ hbf) {
    int t = threadIdx.x;
    int n = blockIdx.x * 2 + (t >> 7);
    if (n >= N_NODES) return;
    int tt = t & 127;
    int c0 = tt * 2;           // columns c0, c0+1
    int h = tt >> 5;           // head
    float ern = er[n * NH + h];
    int r0 = rowptr[n], r1 = rowptr[n + 1];
    float acc0 = 0.f, acc1 = 0.f, S = 0.f;
    int i = r0;
    for (; i + 2 <= r1; i += 2) {
        int s0 = esrc[i], s1 = esrc[i + 1];
        uint p0 = *(const uint*)&featbf[s0 * F + c0];
        uint p1 = *(const uint*)&featbf[s1 * F + c0];
        float e0 = el[s0 * NH + h] + ern;
        float e1 = el[s1 * NH + h] + ern;
        e0 = e0 > 0.f ? e0 : NEG_SLOPE * e0;
        e1 = e1 > 0.f ? e1 : NEG_SLOPE * e1;
        float a0 = __expf(e0), a1 = __expf(e1);
        S += a0 + a1;
        acc0 += a0 * bf2f((ushort)(p0 & 0xFFFF)) + a1 * bf2f((ushort)(p1 & 0xFFFF));
        acc1 += a0 * bf2f((ushort)(p0 >> 16))    + a1 * bf2f((ushort)(p1 >> 16));
    }
    if (i < r1) {
        int s0 = esrc[i];
        uint p0 = *(const uint*)&featbf[s0 * F + c0];
        float e0 = el[s0 * NH + h] + ern;
        e0 = e0 > 0.f ? e0 : NEG_SLOPE * e0;
        float a0 = __expf(e0);
        S += a0;
        acc0 += a0 * bf2f((ushort)(p0 & 0xFFFF));
        acc1 += a0 * bf2f((ushort)(p0 >> 16));
    }
    float inv = S > 0.f ? 1.f / S : 0.f;
    float o0 = acc0 * inv + bias[c0];
    float o1 = acc1 * inv + bias[c0 + 1];
    o0 = o0 > 0.f ? o0 : 0.f;
    o1 = o1 > 0.f ? o1 : 0.f;
    uint pk = (uint)f2bf(o0) | ((uint)f2bf(o1) << 16);
    *(uint*)&hbf[n * F + c0] = pk;
}

// ---------- final dot scores: 16 lanes per edge, 4 edges per wave ----------
__global__ __launch_bounds__(256) void k_score(const ushort* __restrict__ h,
        const int* __restrict__ src, const int* __restrict__ dst,
        const int* __restrict__ nsrc, const int* __restrict__ ndst,
        float* __restrict__ out) {
    int g = blockIdx.x * 16 + (threadIdx.x >> 4);   // edge slot 0..2E-1
    int sub = threadIdx.x & 15;                     // 16B segment within row
    int u, v;
    float* o;
    if (g < N_EDGES) {
        u = src[g]; v = dst[g]; o = out + (size_t)g * NH;
    } else {
        int e = g - N_EDGES;
        u = nsrc[e]; v = ndst[e];
        o = out + (size_t)(N_EDGES + e) * NH;
    }
    u16x8 a0 = *(const u16x8*)&h[u * F + sub * 16];
    u16x8 a1 = *(const u16x8*)&h[u * F + sub * 16 + 8];
    u16x8 b0 = *(const u16x8*)&h[v * F + sub * 16];
    u16x8 b1 = *(const u16x8*)&h[v * F + sub * 16 + 8];
    float p = 0.f;
    #pragma unroll
    for (int i = 0; i < 8; ++i) {
        p += bf2f(a0[i]) * bf2f(b0[i]);
        p += bf2f(a1[i]) * bf2f(b1[i]);
    }
    p += __shfl_xor(p, 1);
    p += __shfl_xor(p, 2);
    if ((sub & 3) == 0) o[sub >> 2] = p;   // head = sub>>2 (4 segs per head)
}

extern "C" void kernel_launch(void* const* d_in, const int* in_sizes, int n_in,
                              void* d_out, int out_size, void* d_ws, size_t ws_size,
                              hipStream_t stream) {
    const float* x    = (const float*)d_in[0];
    const int* src    = (const int*)d_in[1];
    const int* dst    = (const int*)d_in[2];
    const int* nsrc   = (const int*)d_in[3];
    const int* ndst   = (const int*)d_in[4];
    const float* W[3]  = {(const float*)d_in[5], (const float*)d_in[9],  (const float*)d_in[13]};
    const float* al[3] = {(const float*)d_in[6], (const float*)d_in[10], (const float*)d_in[14]};
    const float* ar[3] = {(const float*)d_in[7], (const float*)d_in[11], (const float*)d_in[15]};
    const float* bs[3] = {(const float*)d_in[8], (const float*)d_in[12], (const float*)d_in[16]};

    char* p = (char*)d_ws;
    auto alloc = [&](size_t bytes) {
        char* r = p;
        p += (bytes + 255) & ~size_t(255);
        return r;
    };
    ushort* xbf    = (ushort*)alloc(sizeof(ushort) * N_NODES * F);
    ushort* featbf = (ushort*)alloc(sizeof(ushort) * N_NODES * F);
    ushort* hA     = (ushort*)alloc(sizeof(ushort) * N_NODES * F);
    ushort* hB     = (ushort*)alloc(sizeof(ushort) * N_NODES * F);
    float* el    = (float*)alloc(sizeof(float) * N_NODES * NH);
    float* er    = (float*)alloc(sizeof(float) * N_NODES * NH);
    int* deg     = (int*)alloc(sizeof(int) * N_NODES);
    int* cursor  = (int*)alloc(sizeof(int) * N_NODES);
    int* rowptr  = (int*)alloc(sizeof(int) * (N_NODES + 1));
    int* esrc    = (int*)alloc(sizeof(int) * N_EDGES);
    short* wtHi[3], *wtLo[3];
    for (int i = 0; i < 3; ++i) {
        wtHi[i] = (short*)alloc(sizeof(short) * 256 * 256);
        wtLo[i] = (short*)alloc(sizeof(short) * 256 * 256);
    }

    (void)hipMemsetAsync(deg, 0, sizeof(int) * N_NODES, stream);
    (void)hipMemsetAsync(cursor, 0, sizeof(int) * N_NODES, stream);

    int eb = (N_EDGES + 255) / 256;
    k_cast<<<(N_NODES * F / 4 + 255) / 256, 256, 0, stream>>>(x, xbf);
    k_degree<<<eb, 256, 0, stream>>>(dst, deg);
    k_scan<<<1, 1024, 0, stream>>>(deg, rowptr);
    k_bucket<<<eb, 256, 0, stream>>>(src, dst, rowptr, cursor, esrc);
    for (int L = 0; L < 3; ++L)
        k_wprep<<<16, 256, 0, stream>>>(W[L], wtHi[L], wtLo[L]);

    const ushort* in_h = xbf;
    ushort* outs[3] = {hA, hB, hA};   // h1 dead when h3 is written
    int gemm_grid = (N_NODES + 63) / 64;
    int node_grid = (N_NODES + 1) / 2;
    for (int L = 0; L < 3; ++L) {
        k_gemm<<<gemm_grid, 256, 0, stream>>>(in_h, wtHi[L], wtLo[L], al[L], ar[L],
                                              featbf, el, er, N_NODES);
        k_node<<<node_grid, 256, 0, stream>>>(featbf, el, er, rowptr, esrc, bs[L], outs[L]);
        in_h = outs[L];
    }
    k_score<<<(2 * N_EDGES) / 16, 256, 0, stream>>>(outs[2], src, dst, nsrc, ndst, (float*)d_out);
}

// Round 11
// 367.897 us; speedup vs baseline: 2.6786x; 1.0896x over previous
//
#include <hip/hip_runtime.h>
#include <hip/hip_bf16.h>
#include <math.h>

#define N_NODES 25000
#define N_EDGES 250000
#define NH 4
#define F 256   // H*D
#define NEG_SLOPE 0.2f

typedef float  f32x4 __attribute__((ext_vector_type(4)));
typedef short  s16x8 __attribute__((ext_vector_type(8)));
typedef ushort u16x8 __attribute__((ext_vector_type(8)));

__device__ inline ushort f2bf(float f) {
    uint u = __float_as_uint(f);
    u += 0x7FFF + ((u >> 16) & 1);   // round-to-nearest-even
    return (ushort)(u >> 16);
}
__device__ inline float bf2f(ushort s) { return __uint_as_float(((uint)s) << 16); }

// ---------- x -> bf16 cast ----------
__global__ __launch_bounds__(256) void k_cast(const float* __restrict__ x,
                                              ushort* __restrict__ xb) {
    int i = blockIdx.x * blockDim.x + threadIdx.x;
    if (i * 4 >= N_NODES * F) return;
    float4 v = *(const float4*)&x[i * 4];
    ushort4 o;
    o.x = f2bf(v.x); o.y = f2bf(v.y); o.z = f2bf(v.z); o.w = f2bf(v.w);
    *(ushort4*)&xb[i * 4] = o;
}

// ---------- CSR build ----------
__global__ void k_degree(const int* __restrict__ dst, int* deg) {
    int e = blockIdx.x * blockDim.x + threadIdx.x;
    if (e < N_EDGES) atomicAdd(&deg[dst[e]], 1);
}

__global__ __launch_bounds__(1024) void k_scan(const int* __restrict__ deg, int* rowptr) {
    __shared__ int sums[1024];
    const int CH = 25;
    int t = threadIdx.x;
    int base = t * CH;
    int s = 0;
    for (int i = 0; i < CH; ++i) {
        int idx = base + i;
        if (idx < N_NODES) s += deg[idx];
    }
    sums[t] = s;
    __syncthreads();
    for (int off = 1; off < 1024; off <<= 1) {
        int v = (t >= off) ? sums[t - off] : 0;
        __syncthreads();
        sums[t] += v;
        __syncthreads();
    }
    int prefix = (t == 0) ? 0 : sums[t - 1];
    for (int i = 0; i < CH; ++i) {
        int idx = base + i;
        if (idx < N_NODES) {
            rowptr[idx] = prefix;
            prefix += deg[idx];
        }
    }
    if (t == 1023) rowptr[N_NODES] = prefix;
}

__global__ void k_bucket(const int* __restrict__ src, const int* __restrict__ dst,
                         const int* __restrict__ rowptr, int* cursor,
                         int* esrc, int* edst, int* eid) {
    int e = blockIdx.x * blockDim.x + threadIdx.x;
    if (e >= N_EDGES) return;
    int d = dst[e];
    int p = atomicAdd(&cursor[d], 1);
    int slot = rowptr[d] + p;
    esrc[slot] = src[e];
    edst[slot] = d;
    eid[slot]  = e;
}

// ---------- W prep: transpose to bf16 [n][k] ----------
__global__ __launch_bounds__(256) void k_wprep(const float* __restrict__ W,
        short* __restrict__ Hi) {
    __shared__ float T[64][65];
    int bk = (blockIdx.x & 3) * 64;
    int bn = (blockIdx.x >> 2) * 64;
    int t = threadIdx.x;
    int r = t >> 6, c = t & 63;
    #pragma unroll
    for (int i = 0; i < 64; i += 4)
        T[r + i][c] = W[(bk + r + i) * 256 + bn + c];
    __syncthreads();
    #pragma unroll
    for (int i = 0; i < 64; i += 4) {
        float w = T[c][r + i];
        Hi[(bn + r + i) * 256 + bk + c] = (short)f2bf(w);
    }
}

// ---------- bf16 MFMA GEMM (1 term; feat output is bf16 anyway) + fused el/er ----------
__global__ __launch_bounds__(256) void k_gemm(const ushort* __restrict__ A,
        const short* __restrict__ Wt,
        const float* __restrict__ alv, const float* __restrict__ arv,
        ushort* __restrict__ Cbf, float* __restrict__ el, float* __restrict__ er,
        int M) {
    __shared__ short As[2][64][32];
    __shared__ short Ws[2][256][32];
    int tid = threadIdx.x;
    int w = tid >> 6, l = tid & 63;
    int row0 = blockIdx.x * 64;

    f32x4 acc[4][4];
    #pragma unroll
    for (int i = 0; i < 4; ++i)
        #pragma unroll
        for (int j = 0; j < 4; ++j)
            acc[i][j] = (f32x4){0.f, 0.f, 0.f, 0.f};

    const int sr = tid >> 2;              // staging row 0..63
    const int sk = tid & 3;               // 16B k-slot 0..3
    const int sa = sk ^ ((sr >> 1) & 3);  // swizzled slot

    s16x8 aReg;
    s16x8 whr[4];

    // prologue: chunk 0 -> regs -> buf 0
    {
        int gr = row0 + sr;
        aReg = (s16x8){0,0,0,0,0,0,0,0};
        if (gr < M) aReg = *(const s16x8*)&A[gr * 256 + sk * 8];
        #pragma unroll
        for (int r = 0; r < 4; ++r) {
            int n = sr + 64 * r;
            whr[r] = *(const s16x8*)&Wt[n * 256 + sk * 8];
        }
        *(s16x8*)&As[0][sr][sa * 8] = aReg;
        #pragma unroll
        for (int r = 0; r < 4; ++r) {
            int n = sr + 64 * r;
            int sw = sk ^ ((n >> 1) & 3);
            *(s16x8*)&Ws[0][n][sw * 8] = whr[r];
        }
    }
    __syncthreads();

    const int r16 = l & 15, kg = l >> 4;
    for (int c = 0; c < 8; ++c) {
        const int b = c & 1;
        if (c < 7) {
            int kc = (c + 1) * 32;
            int gr = row0 + sr;
            aReg = (s16x8){0,0,0,0,0,0,0,0};
            if (gr < M) aReg = *(const s16x8*)&A[gr * 256 + kc + sk * 8];
            #pragma unroll
            for (int r = 0; r < 4; ++r) {
                int n = sr + 64 * r;
                whr[r] = *(const s16x8*)&Wt[n * 256 + kc + sk * 8];
            }
        }
        s16x8 ah[4], bh[4];
        #pragma unroll
        for (int i = 0; i < 4; ++i) {
            int r = i * 16 + r16;
            int s = (kg ^ ((r >> 1) & 3)) * 8;
            ah[i] = *(const s16x8*)&As[b][r][s];
        }
        #pragma unroll
        for (int j = 0; j < 4; ++j) {
            int cc = w * 64 + j * 16 + r16;
            int s = (kg ^ ((cc >> 1) & 3)) * 8;
            bh[j] = *(const s16x8*)&Ws[b][cc][s];
        }
        #pragma unroll
        for (int i = 0; i < 4; ++i)
            #pragma unroll
            for (int j = 0; j < 4; ++j)
                acc[i][j] = __builtin_amdgcn_mfma_f32_16x16x32_bf16(ah[i], bh[j], acc[i][j], 0, 0, 0);
        if (c < 7) {
            *(s16x8*)&As[b ^ 1][sr][sa * 8] = aReg;
            #pragma unroll
            for (int r = 0; r < 4; ++r) {
                int n = sr + 64 * r;
                int sw = sk ^ ((n >> 1) & 3);
                *(s16x8*)&Ws[b ^ 1][n][sw * 8] = whr[r];
            }
        }
        __syncthreads();
    }

    // ---- epilogue: fused el/er + bf16 feat write ----
    float ac4[4], rc4[4];
    #pragma unroll
    for (int j = 0; j < 4; ++j) {
        ac4[j] = alv[w * 64 + j * 16 + r16];
        rc4[j] = arv[w * 64 + j * 16 + r16];
    }
    #pragma unroll
    for (int i = 0; i < 4; ++i) {
        #pragma unroll
        for (int q = 0; q < 4; ++q) {
            int gr = row0 + i * 16 + kg * 4 + q;
            float pel = 0.f, per = 0.f;
            #pragma unroll
            for (int j = 0; j < 4; ++j) {
                float v = acc[i][j][q];
                pel += v * ac4[j];
                per += v * rc4[j];
            }
            pel += __shfl_xor(pel, 1);  per += __shfl_xor(per, 1);
            pel += __shfl_xor(pel, 2);  per += __shfl_xor(per, 2);
            pel += __shfl_xor(pel, 4);  per += __shfl_xor(per, 4);
            pel += __shfl_xor(pel, 8);  per += __shfl_xor(per, 8);
            if (r16 == 0 && gr < M) {
                el[gr * NH + w] = pel;
                er[gr * NH + w] = per;
            }
        }
    }
    #pragma unroll
    for (int i = 0; i < 4; ++i)
        #pragma unroll
        for (int j = 0; j < 4; ++j) {
            int cc = w * 64 + j * 16 + r16;
            #pragma unroll
            for (int q = 0; q < 4; ++q) {
                int gr = row0 + i * 16 + kg * 4 + q;
                if (gr < M) Cbf[gr * 256 + cc] = f2bf(acc[i][j][q]);
            }
        }
}

// ---------- fused attention + aggregation: 2 nodes/block, unroll-4 ----------
__global__ __launch_bounds__(256) void k_node(const ushort* __restrict__ featbf,
        const float* __restrict__ el, const float* __restrict__ er,
        const int* __restrict__ rowptr, const int* __restrict__ esrc,
        const float* __restrict__ bias,
        ushort* __restrict__ hbf) {
    int t = threadIdx.x;
    int n = blockIdx.x * 2 + (t >> 7);
    if (n >= N_NODES) return;
    int tt = t & 127;
    int c0 = tt * 2;           // columns c0, c0+1
    int h = tt >> 5;           // head
    float ern = er[n * NH + h];
    int r0 = rowptr[n], r1 = rowptr[n + 1];
    float acc0 = 0.f, acc1 = 0.f, S = 0.f;
    int i = r0;
    for (; i + 4 <= r1; i += 4) {
        int s0 = esrc[i], s1 = esrc[i + 1], s2 = esrc[i + 2], s3 = esrc[i + 3];
        uint p0 = *(const uint*)&featbf[s0 * F + c0];
        uint p1 = *(const uint*)&featbf[s1 * F + c0];
        uint p2 = *(const uint*)&featbf[s2 * F + c0];
        uint p3 = *(const uint*)&featbf[s3 * F + c0];
        float e0 = el[s0 * NH + h] + ern;
        float e1 = el[s1 * NH + h] + ern;
        float e2 = el[s2 * NH + h] + ern;
        float e3 = el[s3 * NH + h] + ern;
        e0 = e0 > 0.f ? e0 : NEG_SLOPE * e0;
        e1 = e1 > 0.f ? e1 : NEG_SLOPE * e1;
        e2 = e2 > 0.f ? e2 : NEG_SLOPE * e2;
        e3 = e3 > 0.f ? e3 : NEG_SLOPE * e3;
        float a0 = __expf(e0), a1 = __expf(e1), a2 = __expf(e2), a3 = __expf(e3);
        S += (a0 + a1) + (a2 + a3);
        acc0 += a0 * bf2f((ushort)(p0 & 0xFFFF)) + a1 * bf2f((ushort)(p1 & 0xFFFF))
              + a2 * bf2f((ushort)(p2 & 0xFFFF)) + a3 * bf2f((ushort)(p3 & 0xFFFF));
        acc1 += a0 * bf2f((ushort)(p0 >> 16))    + a1 * bf2f((ushort)(p1 >> 16))
              + a2 * bf2f((ushort)(p2 >> 16))    + a3 * bf2f((ushort)(p3 >> 16));
    }
    for (; i < r1; ++i) {
        int s0 = esrc[i];
        uint p0 = *(const uint*)&featbf[s0 * F + c0];
        float e0 = el[s0 * NH + h] + ern;
        e0 = e0 > 0.f ? e0 : NEG_SLOPE * e0;
        float a0 = __expf(e0);
        S += a0;
        acc0 += a0 * bf2f((ushort)(p0 & 0xFFFF));
        acc1 += a0 * bf2f((ushort)(p0 >> 16));
    }
    float inv = S > 0.f ? 1.f / S : 0.f;
    float o0 = acc0 * inv + bias[c0];
    float o1 = acc1 * inv + bias[c0 + 1];
    o0 = o0 > 0.f ? o0 : 0.f;
    o1 = o1 > 0.f ? o1 : 0.f;
    uint pk = (uint)f2bf(o0) | ((uint)f2bf(o1) << 16);
    *(uint*)&hbf[n * F + c0] = pk;
}

// ---------- final dot scores: 16 lanes/edge; pos edges walk CSR (dst-sorted) ----------
__global__ __launch_bounds__(256) void k_score(const ushort* __restrict__ h,
        const int* __restrict__ esrc, const int* __restrict__ edst,
        const int* __restrict__ eid,
        const int* __restrict__ nsrc, const int* __restrict__ ndst,
        float* __restrict__ out) {
    int g = blockIdx.x * 16 + (threadIdx.x >> 4);   // edge slot 0..2E-1
    int sub = threadIdx.x & 15;                     // 16B segment within row
    int u, v;
    float* o;
    if (g < N_EDGES) {
        u = esrc[g]; v = edst[g];                   // dst-sorted -> v-row L1 reuse
        o = out + (size_t)eid[g] * NH;
    } else {
        int e = g - N_EDGES;
        u = nsrc[e]; v = ndst[e];
        o = out + (size_t)(N_EDGES + e) * NH;
    }
    u16x8 a0 = *(const u16x8*)&h[u * F + sub * 16];
    u16x8 a1 = *(const u16x8*)&h[u * F + sub * 16 + 8];
    u16x8 b0 = *(const u16x8*)&h[v * F + sub * 16];
    u16x8 b1 = *(const u16x8*)&h[v * F + sub * 16 + 8];
    float p = 0.f;
    #pragma unroll
    for (int i = 0; i < 8; ++i) {
        p += bf2f(a0[i]) * bf2f(b0[i]);
        p += bf2f(a1[i]) * bf2f(b1[i]);
    }
    p += __shfl_xor(p, 1);
    p += __shfl_xor(p, 2);
    if ((sub & 3) == 0) o[sub >> 2] = p;   // head = sub>>2 (4 segs per head)
}

extern "C" void kernel_launch(void* const* d_in, const int* in_sizes, int n_in,
                              void* d_out, int out_size, void* d_ws, size_t ws_size,
                              hipStream_t stream) {
    const float* x    = (const float*)d_in[0];
    const int* src    = (const int*)d_in[1];
    const int* dst    = (const int*)d_in[2];
    const int* nsrc   = (const int*)d_in[3];
    const int* ndst   = (const int*)d_in[4];
    const float* W[3]  = {(const float*)d_in[5], (const float*)d_in[9],  (const float*)d_in[13]};
    const float* al[3] = {(const float*)d_in[6], (const float*)d_in[10], (const float*)d_in[14]};
    const float* ar[3] = {(const float*)d_in[7], (const float*)d_in[11], (const float*)d_in[15]};
    const float* bs[3] = {(const float*)d_in[8], (const float*)d_in[12], (const float*)d_in[16]};

    char* p = (char*)d_ws;
    auto alloc = [&](size_t bytes) {
        char* r = p;
        p += (bytes + 255) & ~size_t(255);
        return r;
    };
    ushort* xbf    = (ushort*)alloc(sizeof(ushort) * N_NODES * F);
    ushort* featbf = (ushort*)alloc(sizeof(ushort) * N_NODES * F);
    ushort* hA     = (ushort*)alloc(sizeof(ushort) * N_NODES * F);
    ushort* hB     = (ushort*)alloc(sizeof(ushort) * N_NODES * F);
    float* el    = (float*)alloc(sizeof(float) * N_NODES * NH);
    float* er    = (float*)alloc(sizeof(float) * N_NODES * NH);
    int* deg     = (int*)alloc(sizeof(int) * N_NODES);
    int* cursor  = (int*)alloc(sizeof(int) * N_NODES);
    int* rowptr  = (int*)alloc(sizeof(int) * (N_NODES + 1));
    int* esrc    = (int*)alloc(sizeof(int) * N_EDGES);
    int* edst    = (int*)alloc(sizeof(int) * N_EDGES);
    int* eid     = (int*)alloc(sizeof(int) * N_EDGES);
    short* wt[3];
    for (int i = 0; i < 3; ++i)
        wt[i] = (short*)alloc(sizeof(short) * 256 * 256);

    (void)hipMemsetAsync(deg, 0, sizeof(int) * N_NODES, stream);
    (void)hipMemsetAsync(cursor, 0, sizeof(int) * N_NODES, stream);

    int eb = (N_EDGES + 255) / 256;
    k_cast<<<(N_NODES * F / 4 + 255) / 256, 256, 0, stream>>>(x, xbf);
    k_degree<<<eb, 256, 0, stream>>>(dst, deg);
    k_scan<<<1, 1024, 0, stream>>>(deg, rowptr);
    k_bucket<<<eb, 256, 0, stream>>>(src, dst, rowptr, cursor, esrc, edst, eid);
    for (int L = 0; L < 3; ++L)
        k_wprep<<<16, 256, 0, stream>>>(W[L], wt[L]);

    const ushort* in_h = xbf;
    ushort* outs[3] = {hA, hB, hA};   // h1 dead by the time h3 is written
    int gemm_grid = (N_NODES + 63) / 64;
    int node_grid = (N_NODES + 1) / 2;
    for (int L = 0; L < 3; ++L) {
        k_gemm<<<gemm_grid, 256, 0, stream>>>(in_h, wt[L], al[L], ar[L],
                                              featbf, el, er, N_NODES);
        k_node<<<node_grid, 256, 0, stream>>>(featbf, el, er, rowptr, esrc, bs[L], outs[L]);
        in_h = outs[L];
    }
    k_score<<<(2 * N_EDGES) / 16, 256, 0, stream>>>(outs[2], esrc, edst, eid, nsrc, ndst, (float*)d_out);
}

// Round 12
// 340.835 us; speedup vs baseline: 2.8912x; 1.0794x over previous
//
#include <hip/hip_runtime.h>
#include <hip/hip_bf16.h>
#include <math.h>

#define N_NODES 25000
#define N_EDGES 250000
#define NH 4
#define F 256   // H*D
#define NEG_SLOPE 0.2f

typedef float  f32x4 __attribute__((ext_vector_type(4)));
typedef short  s16x8 __attribute__((ext_vector_type(8)));
typedef ushort u16x8 __attribute__((ext_vector_type(8)));

__device__ inline ushort f2bf(float f) {
    uint u = __float_as_uint(f);
    u += 0x7FFF + ((u >> 16) & 1);   // round-to-nearest-even
    return (ushort)(u >> 16);
}
__device__ inline float bf2f(ushort s) { return __uint_as_float(((uint)s) << 16); }

// ---------- x -> bf16 cast ----------
__global__ __launch_bounds__(256) void k_cast(const float* __restrict__ x,
                                              ushort* __restrict__ xb) {
    int i = blockIdx.x * blockDim.x + threadIdx.x;
    if (i * 4 >= N_NODES * F) return;
    float4 v = *(const float4*)&x[i * 4];
    ushort4 o;
    o.x = f2bf(v.x); o.y = f2bf(v.y); o.z = f2bf(v.z); o.w = f2bf(v.w);
    *(ushort4*)&xb[i * 4] = o;
}

// ---------- CSR build ----------
__global__ void k_degree(const int* __restrict__ dst, int* deg) {
    int e = blockIdx.x * blockDim.x + threadIdx.x;
    if (e < N_EDGES) atomicAdd(&deg[dst[e]], 1);
}

__global__ __launch_bounds__(1024) void k_scan(const int* __restrict__ deg, int* rowptr) {
    __shared__ int sums[1024];
    const int CH = 25;
    int t = threadIdx.x;
    int base = t * CH;
    int s = 0;
    for (int i = 0; i < CH; ++i) {
        int idx = base + i;
        if (idx < N_NODES) s += deg[idx];
    }
    sums[t] = s;
    __syncthreads();
    for (int off = 1; off < 1024; off <<= 1) {
        int v = (t >= off) ? sums[t - off] : 0;
        __syncthreads();
        sums[t] += v;
        __syncthreads();
    }
    int prefix = (t == 0) ? 0 : sums[t - 1];
    for (int i = 0; i < CH; ++i) {
        int idx = base + i;
        if (idx < N_NODES) {
            rowptr[idx] = prefix;
            prefix += deg[idx];
        }
    }
    if (t == 1023) rowptr[N_NODES] = prefix;
}

__global__ void k_bucket(const int* __restrict__ src, const int* __restrict__ dst,
                         const int* __restrict__ rowptr, int* cursor,
                         int* esrc, int* edst, int* eid) {
    int e = blockIdx.x * blockDim.x + threadIdx.x;
    if (e >= N_EDGES) return;
    int d = dst[e];
    int p = atomicAdd(&cursor[d], 1);
    int slot = rowptr[d] + p;
    esrc[slot] = src[e];
    edst[slot] = d;
    eid[slot]  = e;
}

// ---------- W prep: transpose to bf16 [n][k] ----------
__global__ __launch_bounds__(256) void k_wprep(const float* __restrict__ W,
        short* __restrict__ Hi) {
    __shared__ float T[64][65];
    int bk = (blockIdx.x & 3) * 64;
    int bn = (blockIdx.x >> 2) * 64;
    int t = threadIdx.x;
    int r = t >> 6, c = t & 63;
    #pragma unroll
    for (int i = 0; i < 64; i += 4)
        T[r + i][c] = W[(bk + r + i) * 256 + bn + c];
    __syncthreads();
    #pragma unroll
    for (int i = 0; i < 64; i += 4) {
        float w = T[c][r + i];
        Hi[(bn + r + i) * 256 + bk + c] = (short)f2bf(w);
    }
}

// ---------- bf16 MFMA GEMM (1 term) + fused el/er ----------
__global__ __launch_bounds__(256) void k_gemm(const ushort* __restrict__ A,
        const short* __restrict__ Wt,
        const float* __restrict__ alv, const float* __restrict__ arv,
        ushort* __restrict__ Cbf, float* __restrict__ el, float* __restrict__ er,
        int M) {
    __shared__ short As[2][64][32];
    __shared__ short Ws[2][256][32];
    int tid = threadIdx.x;
    int w = tid >> 6, l = tid & 63;
    int row0 = blockIdx.x * 64;

    f32x4 acc[4][4];
    #pragma unroll
    for (int i = 0; i < 4; ++i)
        #pragma unroll
        for (int j = 0; j < 4; ++j)
            acc[i][j] = (f32x4){0.f, 0.f, 0.f, 0.f};

    const int sr = tid >> 2;              // staging row 0..63
    const int sk = tid & 3;               // 16B k-slot 0..3
    const int sa = sk ^ ((sr >> 1) & 3);  // swizzled slot

    s16x8 aReg;
    s16x8 whr[4];

    {
        int gr = row0 + sr;
        aReg = (s16x8){0,0,0,0,0,0,0,0};
        if (gr < M) aReg = *(const s16x8*)&A[gr * 256 + sk * 8];
        #pragma unroll
        for (int r = 0; r < 4; ++r) {
            int n = sr + 64 * r;
            whr[r] = *(const s16x8*)&Wt[n * 256 + sk * 8];
        }
        *(s16x8*)&As[0][sr][sa * 8] = aReg;
        #pragma unroll
        for (int r = 0; r < 4; ++r) {
            int n = sr + 64 * r;
            int sw = sk ^ ((n >> 1) & 3);
            *(s16x8*)&Ws[0][n][sw * 8] = whr[r];
        }
    }
    __syncthreads();

    const int r16 = l & 15, kg = l >> 4;
    for (int c = 0; c < 8; ++c) {
        const int b = c & 1;
        if (c < 7) {
            int kc = (c + 1) * 32;
            int gr = row0 + sr;
            aReg = (s16x8){0,0,0,0,0,0,0,0};
            if (gr < M) aReg = *(const s16x8*)&A[gr * 256 + kc + sk * 8];
            #pragma unroll
            for (int r = 0; r < 4; ++r) {
                int n = sr + 64 * r;
                whr[r] = *(const s16x8*)&Wt[n * 256 + kc + sk * 8];
            }
        }
        s16x8 ah[4], bh[4];
        #pragma unroll
        for (int i = 0; i < 4; ++i) {
            int r = i * 16 + r16;
            int s = (kg ^ ((r >> 1) & 3)) * 8;
            ah[i] = *(const s16x8*)&As[b][r][s];
        }
        #pragma unroll
        for (int j = 0; j < 4; ++j) {
            int cc = w * 64 + j * 16 + r16;
            int s = (kg ^ ((cc >> 1) & 3)) * 8;
            bh[j] = *(const s16x8*)&Ws[b][cc][s];
        }
        #pragma unroll
        for (int i = 0; i < 4; ++i)
            #pragma unroll
            for (int j = 0; j < 4; ++j)
                acc[i][j] = __builtin_amdgcn_mfma_f32_16x16x32_bf16(ah[i], bh[j], acc[i][j], 0, 0, 0);
        if (c < 7) {
            *(s16x8*)&As[b ^ 1][sr][sa * 8] = aReg;
            #pragma unroll
            for (int r = 0; r < 4; ++r) {
                int n = sr + 64 * r;
                int sw = sk ^ ((n >> 1) & 3);
                *(s16x8*)&Ws[b ^ 1][n][sw * 8] = whr[r];
            }
        }
        __syncthreads();
    }

    // ---- epilogue: fused el/er + bf16 feat write ----
    float ac4[4], rc4[4];
    #pragma unroll
    for (int j = 0; j < 4; ++j) {
        ac4[j] = alv[w * 64 + j * 16 + r16];
        rc4[j] = arv[w * 64 + j * 16 + r16];
    }
    #pragma unroll
    for (int i = 0; i < 4; ++i) {
        #pragma unroll
        for (int q = 0; q < 4; ++q) {
            int gr = row0 + i * 16 + kg * 4 + q;
            float pel = 0.f, per = 0.f;
            #pragma unroll
            for (int j = 0; j < 4; ++j) {
                float v = acc[i][j][q];
                pel += v * ac4[j];
                per += v * rc4[j];
            }
            pel += __shfl_xor(pel, 1);  per += __shfl_xor(per, 1);
            pel += __shfl_xor(pel, 2);  per += __shfl_xor(per, 2);
            pel += __shfl_xor(pel, 4);  per += __shfl_xor(per, 4);
            pel += __shfl_xor(pel, 8);  per += __shfl_xor(per, 8);
            if (r16 == 0 && gr < M) {
                el[gr * NH + w] = pel;
                er[gr * NH + w] = per;
            }
        }
    }
    #pragma unroll
    for (int i = 0; i < 4; ++i)
        #pragma unroll
        for (int j = 0; j < 4; ++j) {
            int cc = w * 64 + j * 16 + r16;
            #pragma unroll
            for (int q = 0; q < 4; ++q) {
                int gr = row0 + i * 16 + kg * 4 + q;
                if (gr < M) Cbf[gr * 256 + cc] = f2bf(acc[i][j][q]);
            }
        }
}

// ---------- fused attention + aggregation: 1 wave/node, 4 nodes/block ----------
// Each lane owns 4 columns (uint2 = 8B gather); one wave-load covers a full
// 512B feat row. Unroll-4 keeps 4 rows (2KB) in flight per wave.
__global__ __launch_bounds__(256) void k_node(const ushort* __restrict__ featbf,
        const float* __restrict__ el, const float* __restrict__ er,
        const int* __restrict__ rowptr, const int* __restrict__ esrc,
        const float* __restrict__ bias,
        ushort* __restrict__ hbf) {
    int t = threadIdx.x;
    int n = blockIdx.x * 4 + (t >> 6);
    if (n >= N_NODES) return;
    int l = t & 63;
    int c0 = l * 4;            // columns c0..c0+3
    int h = l >> 4;            // head (16 lanes per head)
    float ern = er[n * NH + h];
    int r0 = rowptr[n], r1 = rowptr[n + 1];
    float ac0 = 0.f, ac1 = 0.f, ac2 = 0.f, ac3 = 0.f, S = 0.f;
    int i = r0;
    for (; i + 4 <= r1; i += 4) {
        int s0 = esrc[i], s1 = esrc[i + 1], s2 = esrc[i + 2], s3 = esrc[i + 3];
        uint2 p0 = *(const uint2*)&featbf[s0 * F + c0];
        uint2 p1 = *(const uint2*)&featbf[s1 * F + c0];
        uint2 p2 = *(const uint2*)&featbf[s2 * F + c0];
        uint2 p3 = *(const uint2*)&featbf[s3 * F + c0];
        float e0 = el[s0 * NH + h] + ern;
        float e1 = el[s1 * NH + h] + ern;
        float e2 = el[s2 * NH + h] + ern;
        float e3 = el[s3 * NH + h] + ern;
        e0 = e0 > 0.f ? e0 : NEG_SLOPE * e0;
        e1 = e1 > 0.f ? e1 : NEG_SLOPE * e1;
        e2 = e2 > 0.f ? e2 : NEG_SLOPE * e2;
        e3 = e3 > 0.f ? e3 : NEG_SLOPE * e3;
        float a0 = __expf(e0), a1 = __expf(e1), a2 = __expf(e2), a3 = __expf(e3);
        S += (a0 + a1) + (a2 + a3);
        ac0 += a0 * bf2f((ushort)(p0.x & 0xFFFF)) + a1 * bf2f((ushort)(p1.x & 0xFFFF))
             + a2 * bf2f((ushort)(p2.x & 0xFFFF)) + a3 * bf2f((ushort)(p3.x & 0xFFFF));
        ac1 += a0 * bf2f((ushort)(p0.x >> 16))    + a1 * bf2f((ushort)(p1.x >> 16))
             + a2 * bf2f((ushort)(p2.x >> 16))    + a3 * bf2f((ushort)(p3.x >> 16));
        ac2 += a0 * bf2f((ushort)(p0.y & 0xFFFF)) + a1 * bf2f((ushort)(p1.y & 0xFFFF))
             + a2 * bf2f((ushort)(p2.y & 0xFFFF)) + a3 * bf2f((ushort)(p3.y & 0xFFFF));
        ac3 += a0 * bf2f((ushort)(p0.y >> 16))    + a1 * bf2f((ushort)(p1.y >> 16))
             + a2 * bf2f((ushort)(p2.y >> 16))    + a3 * bf2f((ushort)(p3.y >> 16));
    }
    for (; i < r1; ++i) {
        int s0 = esrc[i];
        uint2 p0 = *(const uint2*)&featbf[s0 * F + c0];
        float e0 = el[s0 * NH + h] + ern;
        e0 = e0 > 0.f ? e0 : NEG_SLOPE * e0;
        float a0 = __expf(e0);
        S += a0;
        ac0 += a0 * bf2f((ushort)(p0.x & 0xFFFF));
        ac1 += a0 * bf2f((ushort)(p0.x >> 16));
        ac2 += a0 * bf2f((ushort)(p0.y & 0xFFFF));
        ac3 += a0 * bf2f((ushort)(p0.y >> 16));
    }
    float inv = S > 0.f ? 1.f / S : 0.f;
    float4 bsv = *(const float4*)&bias[c0];
    float o0 = ac0 * inv + bsv.x;
    float o1 = ac1 * inv + bsv.y;
    float o2 = ac2 * inv + bsv.z;
    float o3 = ac3 * inv + bsv.w;
    o0 = o0 > 0.f ? o0 : 0.f;
    o1 = o1 > 0.f ? o1 : 0.f;
    o2 = o2 > 0.f ? o2 : 0.f;
    o3 = o3 > 0.f ? o3 : 0.f;
    uint2 pk;
    pk.x = (uint)f2bf(o0) | ((uint)f2bf(o1) << 16);
    pk.y = (uint)f2bf(o2) | ((uint)f2bf(o3) << 16);
    *(uint2*)&hbf[n * F + c0] = pk;
}

// ---------- final dot scores: 16 lanes/edge; pos edges walk CSR (dst-sorted) ----------
__global__ __launch_bounds__(256) void k_score(const ushort* __restrict__ h,
        const int* __restrict__ esrc, const int* __restrict__ edst,
        const int* __restrict__ eid,
        const int* __restrict__ nsrc, const int* __restrict__ ndst,
        float* __restrict__ out) {
    int g = blockIdx.x * 16 + (threadIdx.x >> 4);   // edge slot 0..2E-1
    int sub = threadIdx.x & 15;                     // 16B segment within row
    int u, v;
    float* o;
    if (g < N_EDGES) {
        u = esrc[g]; v = edst[g];                   // dst-sorted -> v-row L1 reuse
        o = out + (size_t)eid[g] * NH;
    } else {
        int e = g - N_EDGES;
        u = nsrc[e]; v = ndst[e];
        o = out + (size_t)(N_EDGES + e) * NH;
    }
    u16x8 a0 = *(const u16x8*)&h[u * F + sub * 16];
    u16x8 a1 = *(const u16x8*)&h[u * F + sub * 16 + 8];
    u16x8 b0 = *(const u16x8*)&h[v * F + sub * 16];
    u16x8 b1 = *(const u16x8*)&h[v * F + sub * 16 + 8];
    float p = 0.f;
    #pragma unroll
    for (int i = 0; i < 8; ++i) {
        p += bf2f(a0[i]) * bf2f(b0[i]);
        p += bf2f(a1[i]) * bf2f(b1[i]);
    }
    p += __shfl_xor(p, 1);
    p += __shfl_xor(p, 2);
    if ((sub & 3) == 0) o[sub >> 2] = p;   // head = sub>>2 (4 segs per head)
}

extern "C" void kernel_launch(void* const* d_in, const int* in_sizes, int n_in,
                              void* d_out, int out_size, void* d_ws, size_t ws_size,
                              hipStream_t stream) {
    const float* x    = (const float*)d_in[0];
    const int* src    = (const int*)d_in[1];
    const int* dst    = (const int*)d_in[2];
    const int* nsrc   = (const int*)d_in[3];
    const int* ndst   = (const int*)d_in[4];
    const float* W[3]  = {(const float*)d_in[5], (const float*)d_in[9],  (const float*)d_in[13]};
    const float* al[3] = {(const float*)d_in[6], (const float*)d_in[10], (const float*)d_in[14]};
    const float* ar[3] = {(const float*)d_in[7], (const float*)d_in[11], (const float*)d_in[15]};
    const float* bs[3] = {(const float*)d_in[8], (const float*)d_in[12], (const float*)d_in[16]};

    char* p = (char*)d_ws;
    auto alloc = [&](size_t bytes) {
        char* r = p;
        p += (bytes + 255) & ~size_t(255);
        return r;
    };
    ushort* xbf    = (ushort*)alloc(sizeof(ushort) * N_NODES * F);
    ushort* featbf = (ushort*)alloc(sizeof(ushort) * N_NODES * F);
    ushort* hA     = (ushort*)alloc(sizeof(ushort) * N_NODES * F);
    ushort* hB     = (ushort*)alloc(sizeof(ushort) * N_NODES * F);
    float* el    = (float*)alloc(sizeof(float) * N_NODES * NH);
    float* er    = (float*)alloc(sizeof(float) * N_NODES * NH);
    int* deg     = (int*)alloc(sizeof(int) * N_NODES);
    int* cursor  = (int*)alloc(sizeof(int) * N_NODES);
    int* rowptr  = (int*)alloc(sizeof(int) * (N_NODES + 1));
    int* esrc    = (int*)alloc(sizeof(int) * N_EDGES);
    int* edst    = (int*)alloc(sizeof(int) * N_EDGES);
    int* eid     = (int*)alloc(sizeof(int) * N_EDGES);
    short* wt[3];
    for (int i = 0; i < 3; ++i)
        wt[i] = (short*)alloc(sizeof(short) * 256 * 256);

    (void)hipMemsetAsync(deg, 0, sizeof(int) * N_NODES, stream);
    (void)hipMemsetAsync(cursor, 0, sizeof(int) * N_NODES, stream);

    int eb = (N_EDGES + 255) / 256;
    k_cast<<<(N_NODES * F / 4 + 255) / 256, 256, 0, stream>>>(x, xbf);
    k_degree<<<eb, 256, 0, stream>>>(dst, deg);
    k_scan<<<1, 1024, 0, stream>>>(deg, rowptr);
    k_bucket<<<eb, 256, 0, stream>>>(src, dst, rowptr, cursor, esrc, edst, eid);
    for (int L = 0; L < 3; ++L)
        k_wprep<<<16, 256, 0, stream>>>(W[L], wt[L]);

    const ushort* in_h = xbf;
    ushort* outs[3] = {hA, hB, hA};   // h1 dead by the time h3 is written
    int gemm_grid = (N_NODES + 63) / 64;
    int node_grid = (N_NODES + 3) / 4;
    for (int L = 0; L < 3; ++L) {
        k_gemm<<<gemm_grid, 256, 0, stream>>>(in_h, wt[L], al[L], ar[L],
                                              featbf, el, er, N_NODES);
        k_node<<<node_grid, 256, 0, stream>>>(featbf, el, er, rowptr, esrc, bs[L], outs[L]);
        in_h = outs[L];
    }
    k_score<<<(2 * N_EDGES) / 16, 256, 0, stream>>>(outs[2], esrc, edst, eid, nsrc, ndst, (float*)d_out);
}